// Round 3
// baseline (293.737 us; speedup 1.0000x reference)
//
#include <hip/hip_runtime.h>

using short8 = __attribute__((ext_vector_type(8))) short;
using f32x4  = __attribute__((ext_vector_type(4))) float;

// f32 -> bf16 (RNE)
__device__ inline short f2b(float f) {
    unsigned u = __float_as_uint(f);
    return (short)((u + 0x7FFFu + ((u >> 16) & 1u)) >> 16);
}
__device__ inline short8 cvt8(float4 a, float4 b) {
    short8 o;
    o[0] = f2b(a.x); o[1] = f2b(a.y); o[2] = f2b(a.z); o[3] = f2b(a.w);
    o[4] = f2b(b.x); o[5] = f2b(b.y); o[6] = f2b(b.z); o[7] = f2b(b.w);
    return o;
}
// fast tanh: 1 - 2/(e^{2x}+1); correct limits at +-inf
__device__ inline float ftanh(float x) {
    float e = __expf(2.f * x);
    return 1.f - 2.f / (e + 1.f);
}

// ---------------------------------------------------------------------------
// Attention-score kernel: kp = enc @ Ua^T tile (256x128), fused epilogue
// scores[row] += sum_h Va[h] * tanh(kp[row,h] + qp[b,h] + Uab[h]).
// 512 threads = 8 waves (4M x 2N); wave tile 64x64 (FM=4, FN=4); BK=64.
// Register-prefetch 2-phase pipeline; XOR-swizzled LDS (8 chunks of 8 bf16).
__global__ __launch_bounds__(512) void k_attn(
    const float* __restrict__ enc, const float* __restrict__ Ua,
    const float* __restrict__ Uab, const float* __restrict__ qp,
    const float* __restrict__ Va, float* __restrict__ scores) {
    __shared__ short As[256 * 64];
    __shared__ short Bs[128 * 64];
    const int t = threadIdx.x;
    const int l = t & 63, w = t >> 6;
    const int wm = w >> 1, wn = w & 1;
    const int lr = l & 15, lg = l >> 4;
    const int n0 = blockIdx.x * 128;
    const int r0 = blockIdx.y * 256;

    f32x4 acc[4][4];
#pragma unroll
    for (int i = 0; i < 4; ++i)
#pragma unroll
        for (int j = 0; j < 4; ++j) { f32x4 z = {0.f, 0.f, 0.f, 0.f}; acc[i][j] = z; }

    float4 pa[4][2], pb[2][2];

    auto load = [&](int kt) {
#pragma unroll
        for (int i = 0; i < 4; ++i) {
            int s = t + 512 * i, row = s >> 3, ch = s & 7;
            const float* p = enc + (size_t)(r0 + row) * 1024 + kt + ch * 8;
            pa[i][0] = *(const float4*)p;
            pa[i][1] = *(const float4*)(p + 4);
        }
#pragma unroll
        for (int i = 0; i < 2; ++i) {
            int s = t + 512 * i, row = s >> 3, ch = s & 7;
            const float* p = Ua + (size_t)(n0 + row) * 1024 + kt + ch * 8;
            pb[i][0] = *(const float4*)p;
            pb[i][1] = *(const float4*)(p + 4);
        }
    };
    auto store = [&]() {
#pragma unroll
        for (int i = 0; i < 4; ++i) {
            int s = t + 512 * i, row = s >> 3, ch = s & 7;
            *(short8*)&As[row * 64 + ((ch ^ (row & 7)) << 3)] = cvt8(pa[i][0], pa[i][1]);
        }
#pragma unroll
        for (int i = 0; i < 2; ++i) {
            int s = t + 512 * i, row = s >> 3, ch = s & 7;
            *(short8*)&Bs[row * 64 + ((ch ^ (row & 7)) << 3)] = cvt8(pb[i][0], pb[i][1]);
        }
    };
    auto compute = [&]() {
#pragma unroll
        for (int kh = 0; kh < 2; ++kh) {
            short8 a[4], b[4];
#pragma unroll
            for (int i = 0; i < 4; ++i) {
                int row = wm * 64 + i * 16 + lr;
                a[i] = *(short8*)&As[row * 64 + ((((kh << 2) | lg) ^ (row & 7)) << 3)];
            }
#pragma unroll
            for (int j = 0; j < 4; ++j) {
                int row = wn * 64 + j * 16 + lr;
                b[j] = *(short8*)&Bs[row * 64 + ((((kh << 2) | lg) ^ (row & 7)) << 3)];
            }
#pragma unroll
            for (int i = 0; i < 4; ++i)
#pragma unroll
                for (int j = 0; j < 4; ++j)
                    acc[i][j] = __builtin_amdgcn_mfma_f32_16x16x32_bf16(a[i], b[j], acc[i][j], 0, 0, 0);
        }
    };

    load(0);
    store();
    __syncthreads();
    for (int kt = 64; kt < 1024; kt += 64) {
        load(kt);     // prefetch next tile into regs (overlaps compute)
        compute();    // consume current LDS tile
        __syncthreads();
        store();      // regs -> LDS (vmcnt waits here)
        __syncthreads();
    }
    compute();

    // epilogue: tanh + Va-weighted reduce over h
    float va[4], ub[4];
#pragma unroll
    for (int j = 0; j < 4; ++j) {
        int h = n0 + wn * 64 + j * 16 + lr;
        va[j] = Va[h]; ub[j] = Uab[h];
    }
#pragma unroll
    for (int i = 0; i < 4; ++i)
#pragma unroll
        for (int r = 0; r < 4; ++r) {
            int row = r0 + wm * 64 + i * 16 + lg * 4 + r;
            const float* qpb = qp + (row >> 7) * 1024;
            float s = 0.f;
#pragma unroll
            for (int j = 0; j < 4; ++j) {
                int h = n0 + wn * 64 + j * 16 + lr;
                s += va[j] * ftanh(acc[i][j][r] + qpb[h] + ub[j]);
            }
            s += __shfl_xor(s, 1);
            s += __shfl_xor(s, 2);
            s += __shfl_xor(s, 4);
            s += __shfl_xor(s, 8);
            if (lr == 0) atomicAdd(scores + row, s);
        }
}

// ---------------------------------------------------------------------------
// Generic M=64 GEMM: C(64 x N) = A(64 x K) @ [B0|B1](N x K)^T + bias.
// B0 covers k < ksplit (ldb0), B1 covers k >= ksplit (ldb1). Tile 64x128,
// 256 threads = 4 waves (2M x 2N), wave tile 32x64 (FM=2, FN=4), BK=64,
// register-prefetch 2-phase.
__global__ __launch_bounds__(256) void k_gemm(
    const float* __restrict__ A, int lda,
    const float* __restrict__ B0, int ldb0,
    const float* __restrict__ B1, int ldb1, int ksplit,
    const float* __restrict__ bias, float* __restrict__ C, int ldc, int K) {
    __shared__ short As[64 * 64];
    __shared__ short Bs[128 * 64];
    const int t = threadIdx.x;
    const int l = t & 63, w = t >> 6;
    const int wm = w >> 1, wn = w & 1;
    const int lr = l & 15, lg = l >> 4;
    const int n0 = blockIdx.x * 128;

    f32x4 acc[2][4];
#pragma unroll
    for (int i = 0; i < 2; ++i)
#pragma unroll
        for (int j = 0; j < 4; ++j) { f32x4 z = {0.f, 0.f, 0.f, 0.f}; acc[i][j] = z; }

    float4 pa[2][2], pb[4][2];

    auto load = [&](int kt) {
#pragma unroll
        for (int i = 0; i < 2; ++i) {
            int s = t + 256 * i, row = s >> 3, ch = s & 7;
            const float* p = A + (size_t)row * lda + kt + ch * 8;
            pa[i][0] = *(const float4*)p;
            pa[i][1] = *(const float4*)(p + 4);
        }
#pragma unroll
        for (int i = 0; i < 4; ++i) {
            int s = t + 256 * i, row = s >> 3, ch = s & 7;
            int kg = kt + ch * 8;
            const float* p = (kg < ksplit)
                                 ? B0 + (size_t)(n0 + row) * ldb0 + kg
                                 : B1 + (size_t)(n0 + row) * ldb1 + (kg - ksplit);
            pb[i][0] = *(const float4*)p;
            pb[i][1] = *(const float4*)(p + 4);
        }
    };
    auto store = [&]() {
#pragma unroll
        for (int i = 0; i < 2; ++i) {
            int s = t + 256 * i, row = s >> 3, ch = s & 7;
            *(short8*)&As[row * 64 + ((ch ^ (row & 7)) << 3)] = cvt8(pa[i][0], pa[i][1]);
        }
#pragma unroll
        for (int i = 0; i < 4; ++i) {
            int s = t + 256 * i, row = s >> 3, ch = s & 7;
            *(short8*)&Bs[row * 64 + ((ch ^ (row & 7)) << 3)] = cvt8(pb[i][0], pb[i][1]);
        }
    };
    auto compute = [&]() {
#pragma unroll
        for (int kh = 0; kh < 2; ++kh) {
            short8 a[2], b[4];
#pragma unroll
            for (int i = 0; i < 2; ++i) {
                int row = wm * 32 + i * 16 + lr;
                a[i] = *(short8*)&As[row * 64 + ((((kh << 2) | lg) ^ (row & 7)) << 3)];
            }
#pragma unroll
            for (int j = 0; j < 4; ++j) {
                int row = wn * 64 + j * 16 + lr;
                b[j] = *(short8*)&Bs[row * 64 + ((((kh << 2) | lg) ^ (row & 7)) << 3)];
            }
#pragma unroll
            for (int i = 0; i < 2; ++i)
#pragma unroll
                for (int j = 0; j < 4; ++j)
                    acc[i][j] = __builtin_amdgcn_mfma_f32_16x16x32_bf16(a[i], b[j], acc[i][j], 0, 0, 0);
        }
    };

    load(0);
    store();
    __syncthreads();
    for (int kt = 64; kt < K; kt += 64) {
        load(kt);
        compute();
        __syncthreads();
        store();
        __syncthreads();
    }
    compute();

#pragma unroll
    for (int i = 0; i < 2; ++i)
#pragma unroll
        for (int j = 0; j < 4; ++j)
#pragma unroll
            for (int r = 0; r < 4; ++r) {
                int R = wm * 32 + i * 16 + lg * 4 + r;
                int c = n0 + wn * 64 + j * 16 + lr;
                C[(size_t)R * ldc + c] = acc[i][j][r] + (bias ? bias[c] : 0.f);
            }
}

// ---------------------------------------------------------------------------
// gather emb row -> xcat[:,0:1024]; copy h0 -> xcat[:,2048:3072]
__global__ void k_gather(const int* __restrict__ idx, const float* __restrict__ emb,
                         const float* __restrict__ h0, float* __restrict__ xcat) {
    int b = blockIdx.x;
    int row = idx[b];
    const float4* se = (const float4*)(emb + (size_t)row * 1024);
    const float4* sh = (const float4*)(h0 + (size_t)b * 1024);
    float4* d = (float4*)(xcat + (size_t)b * 3072);
    for (int i = threadIdx.x; i < 256; i += blockDim.x) {
        d[i] = se[i];
        d[512 + i] = sh[i];
    }
}

__global__ void k_softmax(const float* __restrict__ scores, float* __restrict__ wout) {
    int b = blockIdx.x;
    int s = threadIdx.x;  // 128
    __shared__ float buf[128];
    float v = scores[b * 128 + s];
    buf[s] = v;
    __syncthreads();
    for (int off = 64; off > 0; off >>= 1) {
        if (s < off) buf[s] = fmaxf(buf[s], buf[s + off]);
        __syncthreads();
    }
    float m = buf[0];
    __syncthreads();
    float e = expf(v - m);
    buf[s] = e;
    __syncthreads();
    for (int off = 64; off > 0; off >>= 1) {
        if (s < off) buf[s] += buf[s + off];
        __syncthreads();
    }
    float sum = buf[0];
    wout[b * 128 + s] = e / sum;
}

// context -> xcat[:,1024:2048]
__global__ void k_context(const float* __restrict__ enc, const float* __restrict__ w,
                          float* __restrict__ xcat) {
    int b = blockIdx.x;
    int t = threadIdx.x;  // 256
    __shared__ float ws[128];
    if (t < 128) ws[t] = w[b * 128 + t];
    __syncthreads();
    float acc[4] = {0.f, 0.f, 0.f, 0.f};
    for (int s = 0; s < 128; ++s) {
        float wv = ws[s];
        const float* row = enc + ((size_t)b * 128 + s) * 1024;
#pragma unroll
        for (int j = 0; j < 4; ++j) acc[j] += wv * row[t + 256 * j];
    }
#pragma unroll
    for (int j = 0; j < 4; ++j) xcat[(size_t)b * 3072 + 1024 + t + 256 * j] = acc[j];
}

__global__ void k_lstm(const float* __restrict__ gates, const float* __restrict__ c0,
                       const float* __restrict__ b_ih, const float* __restrict__ b_hh,
                       float* __restrict__ h1, float* __restrict__ c1) {
    int idx = blockIdx.x * blockDim.x + threadIdx.x;  // 65536
    int b = idx >> 10, h = idx & 1023;
    const float* g = gates + (size_t)b * 4096;
    float iv = g[h] + b_ih[h] + b_hh[h];
    float fv = g[1024 + h] + b_ih[1024 + h] + b_hh[1024 + h];
    float gv = g[2048 + h] + b_ih[2048 + h] + b_hh[2048 + h];
    float ov = g[3072 + h] + b_ih[3072 + h] + b_hh[3072 + h];
    float si = 1.f / (1.f + expf(-iv));
    float sf = 1.f / (1.f + expf(-fv));
    float so = 1.f / (1.f + expf(-ov));
    float tg = tanhf(gv);
    float cc = sf * c0[idx] + si * tg;
    float hh = so * tanhf(cc);
    c1[idx] = cc;
    h1[idx] = hh;
}

// ---------------------------------------------------------------------------
extern "C" void kernel_launch(void* const* d_in, const int* in_sizes, int n_in,
                              void* d_out, int out_size, void* d_ws, size_t ws_size,
                              hipStream_t stream) {
    const int* idx = (const int*)d_in[0];
    const float* hidden = (const float*)d_in[1];
    const float* cell = (const float*)d_in[2];
    const float* enc = (const float*)d_in[3];
    const float* emb = (const float*)d_in[4];
    const float* Wa_w = (const float*)d_in[5];
    const float* Wa_b = (const float*)d_in[6];
    const float* Ua_w = (const float*)d_in[7];
    const float* Ua_b = (const float*)d_in[8];
    const float* Va_w = (const float*)d_in[9];
    // d_in[10] Va_b unused: softmax shift-invariant
    const float* W_ih = (const float*)d_in[11];
    const float* W_hh = (const float*)d_in[12];
    const float* b_ih = (const float*)d_in[13];
    const float* b_hh = (const float*)d_in[14];
    const float* out_w = (const float*)d_in[15];
    const float* out_b = (const float*)d_in[16];

    float* out = (float*)d_out;
    float* logits = out;                             // 64*32000
    float* h1 = out + 2048000;                       // 64*1024
    float* c1 = out + 2048000 + 65536;               // 64*1024
    float* wts = out + 2048000 + 65536 + 65536;      // 64*128

    float* ws = (float*)d_ws;
    float* qp = ws;                    // 65536
    float* scores = ws + 65536;        // 8192
    float* xcat = ws + 65536 + 8192;   // 64*3072 = 196608
    float* gates = xcat + 196608;      // 64*4096 = 262144

    hipMemsetAsync(scores, 0, 8192 * sizeof(float), stream);
    k_gather<<<64, 256, 0, stream>>>(idx, emb, hidden, xcat);
    // qp = h0 @ Wa^T + Wa_b
    k_gemm<<<8, 256, 0, stream>>>(hidden, 1024, Wa_w, 1024, nullptr, 0, 1024,
                                  Wa_b, qp, 1024, 1024);
    // attention scores
    k_attn<<<dim3(8, 32), 512, 0, stream>>>(enc, Ua_w, Ua_b, qp, Va_w, scores);
    k_softmax<<<64, 128, 0, stream>>>(scores, wts);
    k_context<<<64, 256, 0, stream>>>(enc, wts, xcat);
    // gates = xcat @ [W_ih | W_hh]^T  (K = 2048 + 1024)
    k_gemm<<<32, 256, 0, stream>>>(xcat, 3072, W_ih, 2048, W_hh, 1024, 2048,
                                   nullptr, gates, 4096, 3072);
    k_lstm<<<256, 256, 0, stream>>>(gates, cell, b_ih, b_hh, h1, c1);
    // logits = h1 @ out_w^T + out_b
    k_gemm<<<250, 256, 0, stream>>>(h1, 1024, out_w, 1024, nullptr, 0, 1024,
                                    out_b, logits, 32000, 1024);
}

// Round 4
// 212.201 us; speedup vs baseline: 1.3842x; 1.3842x over previous
//
#include <hip/hip_runtime.h>
#include <hip/hip_bf16.h>

using short8 = __attribute__((ext_vector_type(8))) short;
using f32x4  = __attribute__((ext_vector_type(4))) float;

// packed f32x2 -> bf16x2 (RNE) via v_cvt_pk_bf16_f32
__device__ inline unsigned pk2(float lo, float hi) {
    __hip_bfloat162 h = __float22bfloat162_rn(float2{lo, hi});
    return *reinterpret_cast<unsigned*>(&h);
}
__device__ inline short8 cvt8(float4 a, float4 b) {
    union { unsigned u[4]; short8 s; } r;
    r.u[0] = pk2(a.x, a.y); r.u[1] = pk2(a.z, a.w);
    r.u[2] = pk2(b.x, b.y); r.u[3] = pk2(b.z, b.w);
    return r.s;
}
// fast tanh: 1 - 2/(e^{2x}+1)
__device__ inline float ftanh(float x) {
    float e = __expf(2.f * x);
    return 1.f - 2.f / (e + 1.f);
}

// ---------------------------------------------------------------------------
// Attention-score kernel: kp = enc @ Ua^T tile (256x128), fused epilogue
// scores[row] += sum_h Va[h]*tanh(kp[row,h] + qp[b,h] + Wab[h] + Uab[h]).
// 512 threads = 8 waves (4M x 2N), wave tile 64x64, BK=64, reg-prefetch.
__global__ __launch_bounds__(512, 2) void k_attn(
    const float* __restrict__ enc, const float* __restrict__ Ua,
    const float* __restrict__ Uab, const float* __restrict__ Wab,
    const float* __restrict__ qp, const float* __restrict__ Va,
    float* __restrict__ scores) {
    __shared__ short As[256 * 64];
    __shared__ short Bs[128 * 64];
    const int t = threadIdx.x;
    const int l = t & 63, w = t >> 6;
    const int wm = w >> 1, wn = w & 1;
    const int lr = l & 15, lg = l >> 4;
    const int n0 = blockIdx.x * 128;
    const int r0 = blockIdx.y * 256;

    f32x4 acc[4][4];
#pragma unroll
    for (int i = 0; i < 4; ++i)
#pragma unroll
        for (int j = 0; j < 4; ++j) { f32x4 z = {0.f, 0.f, 0.f, 0.f}; acc[i][j] = z; }

    float4 pa[4][2], pb[2][2];

    auto load = [&](int kt) {
#pragma unroll
        for (int i = 0; i < 4; ++i) {
            int s = t + 512 * i, row = s >> 3, ch = s & 7;
            const float* p = enc + (size_t)(r0 + row) * 1024 + kt + ch * 8;
            pa[i][0] = *(const float4*)p;
            pa[i][1] = *(const float4*)(p + 4);
        }
#pragma unroll
        for (int i = 0; i < 2; ++i) {
            int s = t + 512 * i, row = s >> 3, ch = s & 7;
            const float* p = Ua + (size_t)(n0 + row) * 1024 + kt + ch * 8;
            pb[i][0] = *(const float4*)p;
            pb[i][1] = *(const float4*)(p + 4);
        }
    };
    auto store = [&]() {
#pragma unroll
        for (int i = 0; i < 4; ++i) {
            int s = t + 512 * i, row = s >> 3, ch = s & 7;
            *(short8*)&As[row * 64 + ((ch ^ (row & 7)) << 3)] = cvt8(pa[i][0], pa[i][1]);
        }
#pragma unroll
        for (int i = 0; i < 2; ++i) {
            int s = t + 512 * i, row = s >> 3, ch = s & 7;
            *(short8*)&Bs[row * 64 + ((ch ^ (row & 7)) << 3)] = cvt8(pb[i][0], pb[i][1]);
        }
    };
    auto compute = [&]() {
#pragma unroll
        for (int kh = 0; kh < 2; ++kh) {
            short8 a[4], b[4];
#pragma unroll
            for (int i = 0; i < 4; ++i) {
                int row = wm * 64 + i * 16 + lr;
                a[i] = *(short8*)&As[row * 64 + ((((kh << 2) | lg) ^ (row & 7)) << 3)];
            }
#pragma unroll
            for (int j = 0; j < 4; ++j) {
                int row = wn * 64 + j * 16 + lr;
                b[j] = *(short8*)&Bs[row * 64 + ((((kh << 2) | lg) ^ (row & 7)) << 3)];
            }
#pragma unroll
            for (int i = 0; i < 4; ++i)
#pragma unroll
                for (int j = 0; j < 4; ++j)
                    acc[i][j] = __builtin_amdgcn_mfma_f32_16x16x32_bf16(a[i], b[j], acc[i][j], 0, 0, 0);
        }
    };

    load(0);
    store();
    __syncthreads();
    for (int kt = 64; kt < 1024; kt += 64) {
        load(kt);
        compute();
        __syncthreads();
        store();
        __syncthreads();
    }
    compute();

    float va[4], ub[4];
#pragma unroll
    for (int j = 0; j < 4; ++j) {
        int h = n0 + wn * 64 + j * 16 + lr;
        va[j] = Va[h];
        ub[j] = Uab[h] + Wab[h];
    }
#pragma unroll
    for (int i = 0; i < 4; ++i)
#pragma unroll
        for (int r = 0; r < 4; ++r) {
            int row = r0 + wm * 64 + i * 16 + lg * 4 + r;
            const float* qpb = qp + (row >> 7) * 1024;
            float s = 0.f;
#pragma unroll
            for (int j = 0; j < 4; ++j) {
                int h = n0 + wn * 64 + j * 16 + lr;
                s += va[j] * ftanh(acc[i][j][r] + qpb[h] + ub[j]);
            }
            s += __shfl_xor(s, 1);
            s += __shfl_xor(s, 2);
            s += __shfl_xor(s, 4);
            s += __shfl_xor(s, 8);
            if (lr == 0) atomicAdd(scores + row, s);
        }
}

// ---------------------------------------------------------------------------
// Skinny GEMM with split-K: C(64 x N) += A(64 x Ktot) @ B(N x Ktot)^T.
// blockIdx.y = ky selects K-window [ky*Kblk, (ky+1)*Kblk); B = B0 for
// ky < kyB1 (cols ky*Kblk of ldb0), else B1 (cols (ky-kyB1)*Kblk of ldb1).
// Tile 64x128, 256 thr = 4 waves (2M x 2N), BK=32, reg-prefetch.
// EPI: 0 = store + bias (grid.y must be 1), 1 = atomicAdd (C pre-zeroed).
template <int EPI>
__global__ __launch_bounds__(256, 1) void k_gemm(
    const float* __restrict__ A, int lda,
    const float* __restrict__ B0, int ldb0,
    const float* __restrict__ B1, int ldb1, int kyB1,
    const float* __restrict__ bias, float* __restrict__ C, int ldc, int Kblk) {
    __shared__ short As[64 * 32];
    __shared__ short Bs[128 * 32];
    const int t = threadIdx.x;
    const int l = t & 63, w = t >> 6;
    const int wm = w >> 1, wn = w & 1;
    const int lr = l & 15, lg = l >> 4;
    const int n0 = blockIdx.x * 128;
    const int ky = blockIdx.y;

    const float* Ab = A + ky * Kblk;
    const float* Bb;
    int ldb;
    if (ky < kyB1) { Bb = B0 + (size_t)ky * Kblk; ldb = ldb0; }
    else           { Bb = B1 + (size_t)(ky - kyB1) * Kblk; ldb = ldb1; }

    f32x4 acc[2][4];
#pragma unroll
    for (int i = 0; i < 2; ++i)
#pragma unroll
        for (int j = 0; j < 4; ++j) { f32x4 z = {0.f, 0.f, 0.f, 0.f}; acc[i][j] = z; }

    float4 pa[2], pb[2][2];

    auto load = [&](int kt) {
        {
            int row = t >> 2, ch = t & 3;
            const float* p = Ab + (size_t)row * lda + kt + ch * 8;
            pa[0] = *(const float4*)p;
            pa[1] = *(const float4*)(p + 4);
        }
#pragma unroll
        for (int i = 0; i < 2; ++i) {
            int s = t + 256 * i, row = s >> 2, ch = s & 3;
            const float* p = Bb + (size_t)(n0 + row) * ldb + kt + ch * 8;
            pb[i][0] = *(const float4*)p;
            pb[i][1] = *(const float4*)(p + 4);
        }
    };
    auto store = [&]() {
        {
            int row = t >> 2, ch = t & 3;
            *(short8*)&As[row * 32 + ((ch ^ (row & 3)) << 3)] = cvt8(pa[0], pa[1]);
        }
#pragma unroll
        for (int i = 0; i < 2; ++i) {
            int s = t + 256 * i, row = s >> 2, ch = s & 3;
            *(short8*)&Bs[row * 32 + ((ch ^ (row & 3)) << 3)] = cvt8(pb[i][0], pb[i][1]);
        }
    };
    auto compute = [&]() {
        short8 a[2], b[4];
#pragma unroll
        for (int i = 0; i < 2; ++i) {
            int row = wm * 32 + i * 16 + lr;
            a[i] = *(short8*)&As[row * 32 + ((lg ^ (row & 3)) << 3)];
        }
#pragma unroll
        for (int j = 0; j < 4; ++j) {
            int row = wn * 64 + j * 16 + lr;
            b[j] = *(short8*)&Bs[row * 32 + ((lg ^ (row & 3)) << 3)];
        }
#pragma unroll
        for (int i = 0; i < 2; ++i)
#pragma unroll
            for (int j = 0; j < 4; ++j)
                acc[i][j] = __builtin_amdgcn_mfma_f32_16x16x32_bf16(a[i], b[j], acc[i][j], 0, 0, 0);
    };

    load(0);
    store();
    __syncthreads();
    for (int kt = 32; kt < Kblk; kt += 32) {
        load(kt);
        compute();
        __syncthreads();
        store();
        __syncthreads();
    }
    compute();

#pragma unroll
    for (int i = 0; i < 2; ++i)
#pragma unroll
        for (int j = 0; j < 4; ++j)
#pragma unroll
            for (int r = 0; r < 4; ++r) {
                int R = wm * 32 + i * 16 + lg * 4 + r;
                int c = n0 + wn * 64 + j * 16 + lr;
                if constexpr (EPI == 1)
                    atomicAdd(&C[(size_t)R * ldc + c], acc[i][j][r]);
                else
                    C[(size_t)R * ldc + c] = acc[i][j][r] + (bias ? bias[c] : 0.f);
            }
}

// ---------------------------------------------------------------------------
__global__ void k_gather(const int* __restrict__ idx, const float* __restrict__ emb,
                         const float* __restrict__ h0, float* __restrict__ xcat) {
    int b = blockIdx.x;
    int row = idx[b];
    const float4* se = (const float4*)(emb + (size_t)row * 1024);
    const float4* sh = (const float4*)(h0 + (size_t)b * 1024);
    float4* d = (float4*)(xcat + (size_t)b * 3072);
    for (int i = threadIdx.x; i < 256; i += blockDim.x) {
        d[i] = se[i];
        d[512 + i] = sh[i];
    }
}

__global__ void k_softmax(const float* __restrict__ scores, float* __restrict__ wout) {
    int b = blockIdx.x;
    int s = threadIdx.x;  // 128
    __shared__ float buf[128];
    float v = scores[b * 128 + s];
    buf[s] = v;
    __syncthreads();
    for (int off = 64; off > 0; off >>= 1) {
        if (s < off) buf[s] = fmaxf(buf[s], buf[s + off]);
        __syncthreads();
    }
    float m = buf[0];
    __syncthreads();
    float e = expf(v - m);
    buf[s] = e;
    __syncthreads();
    for (int off = 64; off > 0; off >>= 1) {
        if (s < off) buf[s] += buf[s + off];
        __syncthreads();
    }
    float sum = buf[0];
    wout[b * 128 + s] = e / sum;
}

__global__ void k_context(const float* __restrict__ enc, const float* __restrict__ w,
                          float* __restrict__ xcat) {
    int b = blockIdx.x;
    int t = threadIdx.x;  // 256
    __shared__ float ws[128];
    if (t < 128) ws[t] = w[b * 128 + t];
    __syncthreads();
    float acc[4] = {0.f, 0.f, 0.f, 0.f};
    for (int s = 0; s < 128; ++s) {
        float wv = ws[s];
        const float* row = enc + ((size_t)b * 128 + s) * 1024;
#pragma unroll
        for (int j = 0; j < 4; ++j) acc[j] += wv * row[t + 256 * j];
    }
#pragma unroll
    for (int j = 0; j < 4; ++j) xcat[(size_t)b * 3072 + 1024 + t + 256 * j] = acc[j];
}

__global__ void k_lstm(const float* __restrict__ gates, const float* __restrict__ c0,
                       const float* __restrict__ b_ih, const float* __restrict__ b_hh,
                       float* __restrict__ h1, float* __restrict__ c1) {
    int idx = blockIdx.x * blockDim.x + threadIdx.x;  // 65536
    int b = idx >> 10, h = idx & 1023;
    const float* g = gates + (size_t)b * 4096;
    float iv = g[h] + b_ih[h] + b_hh[h];
    float fv = g[1024 + h] + b_ih[1024 + h] + b_hh[1024 + h];
    float gv = g[2048 + h] + b_ih[2048 + h] + b_hh[2048 + h];
    float ov = g[3072 + h] + b_ih[3072 + h] + b_hh[3072 + h];
    float si = 1.f / (1.f + expf(-iv));
    float sf = 1.f / (1.f + expf(-fv));
    float so = 1.f / (1.f + expf(-ov));
    float tg = tanhf(gv);
    float cc = sf * c0[idx] + si * tg;
    float hh = so * tanhf(cc);
    c1[idx] = cc;
    h1[idx] = hh;
}

// ---------------------------------------------------------------------------
extern "C" void kernel_launch(void* const* d_in, const int* in_sizes, int n_in,
                              void* d_out, int out_size, void* d_ws, size_t ws_size,
                              hipStream_t stream) {
    const int* idx = (const int*)d_in[0];
    const float* hidden = (const float*)d_in[1];
    const float* cell = (const float*)d_in[2];
    const float* enc = (const float*)d_in[3];
    const float* emb = (const float*)d_in[4];
    const float* Wa_w = (const float*)d_in[5];
    const float* Wa_b = (const float*)d_in[6];
    const float* Ua_w = (const float*)d_in[7];
    const float* Ua_b = (const float*)d_in[8];
    const float* Va_w = (const float*)d_in[9];
    // d_in[10] Va_b unused: softmax shift-invariant
    const float* W_ih = (const float*)d_in[11];
    const float* W_hh = (const float*)d_in[12];
    const float* b_ih = (const float*)d_in[13];
    const float* b_hh = (const float*)d_in[14];
    const float* out_w = (const float*)d_in[15];
    const float* out_b = (const float*)d_in[16];

    float* out = (float*)d_out;
    float* logits = out;                             // 64*32000
    float* h1 = out + 2048000;                       // 64*1024
    float* c1 = out + 2048000 + 65536;               // 64*1024
    float* wts = out + 2048000 + 65536 + 65536;      // 64*128

    float* ws = (float*)d_ws;
    float* qp = ws;                    // 65536
    float* scores = ws + 65536;        // 8192
    float* xcat = ws + 65536 + 8192;   // 64*3072
    float* gates = xcat + 196608;      // 64*4096

    // zero the atomic-accumulated buffers (qp, scores, gates are contiguous-ish)
    hipMemsetAsync(qp, 0, (65536 + 8192) * sizeof(float), stream);   // qp + scores
    hipMemsetAsync(gates, 0, 262144 * sizeof(float), stream);
    k_gather<<<64, 256, 0, stream>>>(idx, emb, hidden, xcat);
    // qp = h0 @ Wa^T (no bias; Wa_b folded into attn epilogue), split-K x2
    k_gemm<1><<<dim3(8, 2), 256, 0, stream>>>(hidden, 1024, Wa_w, 1024,
                                              nullptr, 0, 99, nullptr, qp, 1024, 512);
    k_attn<<<dim3(8, 32), 512, 0, stream>>>(enc, Ua_w, Ua_b, Wa_b, qp, Va_w, scores);
    k_softmax<<<64, 128, 0, stream>>>(scores, wts);
    k_context<<<64, 256, 0, stream>>>(enc, wts, xcat);
    // gates = xcat @ [W_ih | W_hh]^T, split-K x3 (ky 0,1 -> W_ih; ky 2 -> W_hh)
    k_gemm<1><<<dim3(32, 3), 256, 0, stream>>>(xcat, 3072, W_ih, 2048,
                                               W_hh, 1024, 2, nullptr, gates, 4096, 1024);
    k_lstm<<<256, 256, 0, stream>>>(gates, cell, b_ih, b_hh, h1, c1);
    // logits = h1 @ out_w^T + out_b
    k_gemm<0><<<dim3(250, 1), 256, 0, stream>>>(h1, 1024, out_w, 1024,
                                                nullptr, 0, 1, out_b, logits, 32000, 1024);
}

// Round 5
// 212.195 us; speedup vs baseline: 1.3843x; 1.0000x over previous
//
#include <hip/hip_runtime.h>
#include <hip/hip_bf16.h>

using short8 = __attribute__((ext_vector_type(8))) short;
using f32x4  = __attribute__((ext_vector_type(4))) float;

// packed f32x2 -> bf16x2 (RNE) via v_cvt_pk_bf16_f32
__device__ inline unsigned pk2(float lo, float hi) {
    __hip_bfloat162 h = __float22bfloat162_rn(float2{lo, hi});
    return *reinterpret_cast<unsigned*>(&h);
}
__device__ inline short8 cvt8(float4 a, float4 b) {
    union { unsigned u[4]; short8 s; } r;
    r.u[0] = pk2(a.x, a.y); r.u[1] = pk2(a.z, a.w);
    r.u[2] = pk2(b.x, b.y); r.u[3] = pk2(b.z, b.w);
    return r.s;
}
// fast tanh: 1 - 2/(e^{2x}+1)
__device__ inline float ftanh(float x) {
    float e = __expf(2.f * x);
    return 1.f - 2.f / (e + 1.f);
}

// async global->LDS, 16 bytes per lane. LDS dest must be wave-uniform base;
// HW scatters base + lane*16. Global src is per-lane.
__device__ inline void gload16(const void* g, void* lds) {
    __builtin_amdgcn_global_load_lds(
        (const __attribute__((address_space(1))) unsigned int*)g,
        (__attribute__((address_space(3))) unsigned int*)lds, 16, 0, 0);
}

// ---------------------------------------------------------------------------
// f32 -> bf16 conversion with granule pre-swizzle. ncols fixed at 1024
// (128 granules of 8 elems / row). Output granule gi holds input granule
// (gi&7)^(row&7) of the same 8-granule (128B) segment:
//   dst[row][seg][g] = cvt(src[row][seg][g ^ (row&7)])
// so that linear global_load_lds staging + XOR'd ds_read is conflict-reduced.
__global__ void k_cvt_swz(const float* __restrict__ src, short* __restrict__ dst,
                          int granules) {
    int i = blockIdx.x * blockDim.x + threadIdx.x;
    if (i >= granules) return;
    int row = i >> 7, gi = i & 127;
    int seg = gi >> 3, g = gi & 7;
    const float* p = src + ((size_t)row << 10) + (seg << 6) + ((g ^ (row & 7)) << 3);
    float4 v0 = *(const float4*)p;
    float4 v1 = *(const float4*)(p + 4);
    *(short8*)&dst[(size_t)i << 3] = cvt8(v0, v1);
}

// ---------------------------------------------------------------------------
// Attention-score GEMM on pre-converted, pre-swizzled bf16 inputs.
// kp = enc_bf(8192x1024) @ Ua_bf^T, tile 128x128, BK=64, staged via
// global_load_lds (linear LDS dest). Fused epilogue:
// scores[row] += sum_h Va[h]*tanh(kp[row,h] + qp[b,h] + Uab[h] + Wab[h]).
// 256 threads = 4 waves (2M x 2N), wave tile 64x64.
__global__ __launch_bounds__(256) void k_attn2(
    const short* __restrict__ Abf, const short* __restrict__ Bbf,
    const float* __restrict__ Uab, const float* __restrict__ Wab,
    const float* __restrict__ qp, const float* __restrict__ Va,
    float* __restrict__ scores) {
    __shared__ short As[128 * 64];
    __shared__ short Bs[128 * 64];
    const int t = threadIdx.x;
    const int l = t & 63, w = t >> 6;
    const int wm = w >> 1, wn = w & 1;
    const int lr = l & 15, lg = l >> 4;
    const int n0 = blockIdx.x * 128;
    const int r0 = blockIdx.y * 128;
    const int lrow8 = l >> 3, lgr = l & 7;

    f32x4 acc[4][4];
#pragma unroll
    for (int i = 0; i < 4; ++i)
#pragma unroll
        for (int j = 0; j < 4; ++j) { f32x4 z = {0.f, 0.f, 0.f, 0.f}; acc[i][j] = z; }

    for (int seg = 0; seg < 16; ++seg) {
#pragma unroll
        for (int i = 0; i < 4; ++i) {
            int arow = w * 32 + i * 8;  // wave-uniform
            gload16(Abf + (size_t)(r0 + arow + lrow8) * 1024 + seg * 64 + lgr * 8,
                    (void*)&As[arow * 64]);
            gload16(Bbf + (size_t)(n0 + arow + lrow8) * 1024 + seg * 64 + lgr * 8,
                    (void*)&Bs[arow * 64]);
        }
        __syncthreads();
#pragma unroll
        for (int kh = 0; kh < 2; ++kh) {
            short8 a[4], b[4];
#pragma unroll
            for (int i = 0; i < 4; ++i) {
                int ra = wm * 64 + i * 16 + lr;
                a[i] = *(const short8*)&As[ra * 64 + (((kh * 4 + lg) ^ (ra & 7)) << 3)];
                int rb = wn * 64 + i * 16 + lr;
                b[i] = *(const short8*)&Bs[rb * 64 + (((kh * 4 + lg) ^ (rb & 7)) << 3)];
            }
#pragma unroll
            for (int i = 0; i < 4; ++i)
#pragma unroll
                for (int j = 0; j < 4; ++j)
                    acc[i][j] = __builtin_amdgcn_mfma_f32_16x16x32_bf16(a[i], b[j], acc[i][j], 0, 0, 0);
        }
        __syncthreads();
    }

    // epilogue: 128 rows == one batch
    const float* qpb = qp + blockIdx.y * 1024;
    float va[4], ub[4];
#pragma unroll
    for (int j = 0; j < 4; ++j) {
        int h = n0 + wn * 64 + j * 16 + lr;
        va[j] = Va[h];
        ub[j] = Uab[h] + Wab[h];
    }
#pragma unroll
    for (int i = 0; i < 4; ++i)
#pragma unroll
        for (int r = 0; r < 4; ++r) {
            int row = r0 + wm * 64 + i * 16 + lg * 4 + r;
            float s = 0.f;
#pragma unroll
            for (int j = 0; j < 4; ++j) {
                int h = n0 + wn * 64 + j * 16 + lr;
                s += va[j] * ftanh(acc[i][j][r] + qpb[h] + ub[j]);
            }
            s += __shfl_xor(s, 1);
            s += __shfl_xor(s, 2);
            s += __shfl_xor(s, 4);
            s += __shfl_xor(s, 8);
            if (lr == 0) atomicAdd(scores + row, s);
        }
}

// ---------------------------------------------------------------------------
// Fallback attention kernel (f32 in-kernel convert), used if ws too small.
__global__ __launch_bounds__(512, 2) void k_attn(
    const float* __restrict__ enc, const float* __restrict__ Ua,
    const float* __restrict__ Uab, const float* __restrict__ Wab,
    const float* __restrict__ qp, const float* __restrict__ Va,
    float* __restrict__ scores) {
    __shared__ short As[256 * 64];
    __shared__ short Bs[128 * 64];
    const int t = threadIdx.x;
    const int l = t & 63, w = t >> 6;
    const int wm = w >> 1, wn = w & 1;
    const int lr = l & 15, lg = l >> 4;
    const int n0 = blockIdx.x * 128;
    const int r0 = blockIdx.y * 256;

    f32x4 acc[4][4];
#pragma unroll
    for (int i = 0; i < 4; ++i)
#pragma unroll
        for (int j = 0; j < 4; ++j) { f32x4 z = {0.f, 0.f, 0.f, 0.f}; acc[i][j] = z; }

    auto stage = [&](int kt) {
#pragma unroll
        for (int i = 0; i < 4; ++i) {
            int s = t + 512 * i, row = s >> 3, ch = s & 7;
            const float* p = enc + (size_t)(r0 + row) * 1024 + kt + ch * 8;
            *(short8*)&As[row * 64 + ((ch ^ (row & 7)) << 3)] =
                cvt8(*(const float4*)p, *(const float4*)(p + 4));
        }
#pragma unroll
        for (int i = 0; i < 2; ++i) {
            int s = t + 512 * i, row = s >> 3, ch = s & 7;
            const float* p = Ua + (size_t)(n0 + row) * 1024 + kt + ch * 8;
            *(short8*)&Bs[row * 64 + ((ch ^ (row & 7)) << 3)] =
                cvt8(*(const float4*)p, *(const float4*)(p + 4));
        }
    };
    auto compute = [&]() {
#pragma unroll
        for (int kh = 0; kh < 2; ++kh) {
            short8 a[4], b[4];
#pragma unroll
            for (int i = 0; i < 4; ++i) {
                int row = wm * 64 + i * 16 + lr;
                a[i] = *(short8*)&As[row * 64 + ((((kh << 2) | lg) ^ (row & 7)) << 3)];
            }
#pragma unroll
            for (int j = 0; j < 4; ++j) {
                int row = wn * 64 + j * 16 + lr;
                b[j] = *(short8*)&Bs[row * 64 + ((((kh << 2) | lg) ^ (row & 7)) << 3)];
            }
#pragma unroll
            for (int i = 0; i < 4; ++i)
#pragma unroll
                for (int j = 0; j < 4; ++j)
                    acc[i][j] = __builtin_amdgcn_mfma_f32_16x16x32_bf16(a[i], b[j], acc[i][j], 0, 0, 0);
        }
    };

    for (int kt = 0; kt < 1024; kt += 64) {
        stage(kt);
        __syncthreads();
        compute();
        __syncthreads();
    }

    float va[4], ub[4];
#pragma unroll
    for (int j = 0; j < 4; ++j) {
        int h = n0 + wn * 64 + j * 16 + lr;
        va[j] = Va[h];
        ub[j] = Uab[h] + Wab[h];
    }
#pragma unroll
    for (int i = 0; i < 4; ++i)
#pragma unroll
        for (int r = 0; r < 4; ++r) {
            int row = r0 + wm * 64 + i * 16 + lg * 4 + r;
            const float* qpb = qp + (row >> 7) * 1024;
            float s = 0.f;
#pragma unroll
            for (int j = 0; j < 4; ++j) {
                int h = n0 + wn * 64 + j * 16 + lr;
                s += va[j] * ftanh(acc[i][j][r] + qpb[h] + ub[j]);
            }
            s += __shfl_xor(s, 1);
            s += __shfl_xor(s, 2);
            s += __shfl_xor(s, 4);
            s += __shfl_xor(s, 8);
            if (lr == 0) atomicAdd(scores + row, s);
        }
}

// ---------------------------------------------------------------------------
// Skinny GEMM with split-K (unchanged from R4).
template <int EPI>
__global__ __launch_bounds__(256, 1) void k_gemm(
    const float* __restrict__ A, int lda,
    const float* __restrict__ B0, int ldb0,
    const float* __restrict__ B1, int ldb1, int kyB1,
    const float* __restrict__ bias, float* __restrict__ C, int ldc, int Kblk) {
    __shared__ short As[64 * 32];
    __shared__ short Bs[128 * 32];
    const int t = threadIdx.x;
    const int l = t & 63, w = t >> 6;
    const int wm = w >> 1, wn = w & 1;
    const int lr = l & 15, lg = l >> 4;
    const int n0 = blockIdx.x * 128;
    const int ky = blockIdx.y;

    const float* Ab = A + ky * Kblk;
    const float* Bb;
    int ldb;
    if (ky < kyB1) { Bb = B0 + (size_t)ky * Kblk; ldb = ldb0; }
    else           { Bb = B1 + (size_t)(ky - kyB1) * Kblk; ldb = ldb1; }

    f32x4 acc[2][4];
#pragma unroll
    for (int i = 0; i < 2; ++i)
#pragma unroll
        for (int j = 0; j < 4; ++j) { f32x4 z = {0.f, 0.f, 0.f, 0.f}; acc[i][j] = z; }

    float4 pa[2], pb[2][2];

    auto load = [&](int kt) {
        {
            int row = t >> 2, ch = t & 3;
            const float* p = Ab + (size_t)row * lda + kt + ch * 8;
            pa[0] = *(const float4*)p;
            pa[1] = *(const float4*)(p + 4);
        }
#pragma unroll
        for (int i = 0; i < 2; ++i) {
            int s = t + 256 * i, row = s >> 2, ch = s & 3;
            const float* p = Bb + (size_t)(n0 + row) * ldb + kt + ch * 8;
            pb[i][0] = *(const float4*)p;
            pb[i][1] = *(const float4*)(p + 4);
        }
    };
    auto store = [&]() {
        {
            int row = t >> 2, ch = t & 3;
            *(short8*)&As[row * 32 + ((ch ^ (row & 3)) << 3)] = cvt8(pa[0], pa[1]);
        }
#pragma unroll
        for (int i = 0; i < 2; ++i) {
            int s = t + 256 * i, row = s >> 2, ch = s & 3;
            *(short8*)&Bs[row * 32 + ((ch ^ (row & 3)) << 3)] = cvt8(pb[i][0], pb[i][1]);
        }
    };
    auto compute = [&]() {
        short8 a[2], b[4];
#pragma unroll
        for (int i = 0; i < 2; ++i) {
            int row = wm * 32 + i * 16 + lr;
            a[i] = *(short8*)&As[row * 32 + ((lg ^ (row & 3)) << 3)];
        }
#pragma unroll
        for (int j = 0; j < 4; ++j) {
            int row = wn * 64 + j * 16 + lr;
            b[j] = *(short8*)&Bs[row * 32 + ((lg ^ (row & 3)) << 3)];
        }
#pragma unroll
        for (int i = 0; i < 2; ++i)
#pragma unroll
            for (int j = 0; j < 4; ++j)
                acc[i][j] = __builtin_amdgcn_mfma_f32_16x16x32_bf16(a[i], b[j], acc[i][j], 0, 0, 0);
    };

    load(0);
    store();
    __syncthreads();
    for (int kt = 32; kt < Kblk; kt += 32) {
        load(kt);
        compute();
        __syncthreads();
        store();
        __syncthreads();
    }
    compute();

#pragma unroll
    for (int i = 0; i < 2; ++i)
#pragma unroll
        for (int j = 0; j < 4; ++j)
#pragma unroll
            for (int r = 0; r < 4; ++r) {
                int R = wm * 32 + i * 16 + lg * 4 + r;
                int c = n0 + wn * 64 + j * 16 + lr;
                if constexpr (EPI == 1)
                    atomicAdd(&C[(size_t)R * ldc + c], acc[i][j][r]);
                else
                    C[(size_t)R * ldc + c] = acc[i][j][r] + (bias ? bias[c] : 0.f);
            }
}

// ---------------------------------------------------------------------------
__global__ void k_gather(const int* __restrict__ idx, const float* __restrict__ emb,
                         const float* __restrict__ h0, float* __restrict__ xcat) {
    int b = blockIdx.x;
    int row = idx[b];
    const float4* se = (const float4*)(emb + (size_t)row * 1024);
    const float4* sh = (const float4*)(h0 + (size_t)b * 1024);
    float4* d = (float4*)(xcat + (size_t)b * 3072);
    for (int i = threadIdx.x; i < 256; i += blockDim.x) {
        d[i] = se[i];
        d[512 + i] = sh[i];
    }
}

__global__ void k_softmax(const float* __restrict__ scores, float* __restrict__ wout) {
    int b = blockIdx.x;
    int s = threadIdx.x;  // 128
    __shared__ float buf[128];
    float v = scores[b * 128 + s];
    buf[s] = v;
    __syncthreads();
    for (int off = 64; off > 0; off >>= 1) {
        if (s < off) buf[s] = fmaxf(buf[s], buf[s + off]);
        __syncthreads();
    }
    float m = buf[0];
    __syncthreads();
    float e = expf(v - m);
    buf[s] = e;
    __syncthreads();
    for (int off = 64; off > 0; off >>= 1) {
        if (s < off) buf[s] += buf[s + off];
        __syncthreads();
    }
    float sum = buf[0];
    wout[b * 128 + s] = e / sum;
}

__global__ void k_context(const float* __restrict__ enc, const float* __restrict__ w,
                          float* __restrict__ xcat) {
    int b = blockIdx.x;
    int t = threadIdx.x;  // 256
    __shared__ float ws[128];
    if (t < 128) ws[t] = w[b * 128 + t];
    __syncthreads();
    float acc[4] = {0.f, 0.f, 0.f, 0.f};
    for (int s = 0; s < 128; ++s) {
        float wv = ws[s];
        const float* row = enc + ((size_t)b * 128 + s) * 1024;
#pragma unroll
        for (int j = 0; j < 4; ++j) acc[j] += wv * row[t + 256 * j];
    }
#pragma unroll
    for (int j = 0; j < 4; ++j) xcat[(size_t)b * 3072 + 1024 + t + 256 * j] = acc[j];
}

__global__ void k_lstm(const float* __restrict__ gates, const float* __restrict__ c0,
                       const float* __restrict__ b_ih, const float* __restrict__ b_hh,
                       float* __restrict__ h1, float* __restrict__ c1) {
    int idx = blockIdx.x * blockDim.x + threadIdx.x;  // 65536
    int b = idx >> 10, h = idx & 1023;
    const float* g = gates + (size_t)b * 4096;
    float iv = g[h] + b_ih[h] + b_hh[h];
    float fv = g[1024 + h] + b_ih[1024 + h] + b_hh[1024 + h];
    float gv = g[2048 + h] + b_ih[2048 + h] + b_hh[2048 + h];
    float ov = g[3072 + h] + b_ih[3072 + h] + b_hh[3072 + h];
    float si = 1.f / (1.f + expf(-iv));
    float sf = 1.f / (1.f + expf(-fv));
    float so = 1.f / (1.f + expf(-ov));
    float tg = tanhf(gv);
    float cc = sf * c0[idx] + si * tg;
    float hh = so * tanhf(cc);
    c1[idx] = cc;
    h1[idx] = hh;
}

// ---------------------------------------------------------------------------
extern "C" void kernel_launch(void* const* d_in, const int* in_sizes, int n_in,
                              void* d_out, int out_size, void* d_ws, size_t ws_size,
                              hipStream_t stream) {
    const int* idx = (const int*)d_in[0];
    const float* hidden = (const float*)d_in[1];
    const float* cell = (const float*)d_in[2];
    const float* enc = (const float*)d_in[3];
    const float* emb = (const float*)d_in[4];
    const float* Wa_w = (const float*)d_in[5];
    const float* Wa_b = (const float*)d_in[6];
    const float* Ua_w = (const float*)d_in[7];
    const float* Ua_b = (const float*)d_in[8];
    const float* Va_w = (const float*)d_in[9];
    // d_in[10] Va_b unused: softmax shift-invariant
    const float* W_ih = (const float*)d_in[11];
    const float* W_hh = (const float*)d_in[12];
    const float* b_ih = (const float*)d_in[13];
    const float* b_hh = (const float*)d_in[14];
    const float* out_w = (const float*)d_in[15];
    const float* out_b = (const float*)d_in[16];

    float* out = (float*)d_out;
    float* logits = out;                             // 64*32000
    float* h1 = out + 2048000;                       // 64*1024
    float* c1 = out + 2048000 + 65536;               // 64*1024
    float* wts = out + 2048000 + 65536 + 65536;      // 64*128

    float* ws = (float*)d_ws;
    float* qp = ws;                    // 65536
    float* scores = ws + 65536;        // 8192
    float* xcat = ws + 65536 + 8192;   // 64*3072 = 196608
    float* gates = xcat + 196608;      // 64*4096 = 262144
    // bf16 staging area after the f32 scratch (532480 floats)
    short* enc_bf = (short*)(ws + 532480);           // 8192*1024 bf16 = 16 MB
    short* ua_bf  = enc_bf + 8192 * 1024;            // 1024*1024 bf16 = 2 MB
    const size_t ws_need = 532480u * 4u + (8192u * 1024u + 1024u * 1024u) * 2u;
    const bool big_ws = ws_size >= ws_need;

    hipMemsetAsync(qp, 0, (65536 + 8192) * sizeof(float), stream);  // qp + scores
    hipMemsetAsync(gates, 0, 262144 * sizeof(float), stream);

    if (big_ws) {
        k_cvt_swz<<<4096, 256, 0, stream>>>(enc, enc_bf, 8192 * 128);
        k_cvt_swz<<<512, 256, 0, stream>>>(Ua_w, ua_bf, 1024 * 128);
    }
    k_gather<<<64, 256, 0, stream>>>(idx, emb, hidden, xcat);
    // qp = h0 @ Wa^T (Wa_b folded into attn epilogue), split-K x2
    k_gemm<1><<<dim3(8, 2), 256, 0, stream>>>(hidden, 1024, Wa_w, 1024,
                                              nullptr, 0, 99, nullptr, qp, 1024, 512);
    if (big_ws)
        k_attn2<<<dim3(8, 64), 256, 0, stream>>>(enc_bf, ua_bf, Ua_b, Wa_b, qp, Va_w, scores);
    else
        k_attn<<<dim3(8, 32), 512, 0, stream>>>(enc, Ua_w, Ua_b, Wa_b, qp, Va_w, scores);
    k_softmax<<<64, 128, 0, stream>>>(scores, wts);
    k_context<<<64, 256, 0, stream>>>(enc, wts, xcat);
    // gates = xcat @ [W_ih | W_hh]^T, split-K x3
    k_gemm<1><<<dim3(32, 3), 256, 0, stream>>>(xcat, 3072, W_ih, 2048,
                                               W_hh, 1024, 2, nullptr, gates, 4096, 1024);
    k_lstm<<<256, 256, 0, stream>>>(gates, cell, b_ih, b_hh, h1, c1);
    // logits = h1 @ out_w^T + out_b
    k_gemm<0><<<dim3(250, 1), 256, 0, stream>>>(h1, 1024, out_w, 1024,
                                                nullptr, 0, 1, out_b, logits, 32000, 1024);
}

// Round 6
// 146.829 us; speedup vs baseline: 2.0005x; 1.4452x over previous
//
#include <hip/hip_runtime.h>
#include <hip/hip_bf16.h>

using short8 = __attribute__((ext_vector_type(8))) short;
using f32x4  = __attribute__((ext_vector_type(4))) float;

// packed f32x2 -> bf16x2 (RNE) via v_cvt_pk_bf16_f32
__device__ inline unsigned pk2(float lo, float hi) {
    __hip_bfloat162 h = __float22bfloat162_rn(float2{lo, hi});
    return *reinterpret_cast<unsigned*>(&h);
}
__device__ inline short8 cvt8(float4 a, float4 b) {
    union { unsigned u[4]; short8 s; } r;
    r.u[0] = pk2(a.x, a.y); r.u[1] = pk2(a.z, a.w);
    r.u[2] = pk2(b.x, b.y); r.u[3] = pk2(b.z, b.w);
    return r.s;
}
// fast tanh: 1 - 2/(e^{2x}+1)
__device__ inline float ftanh(float x) {
    float e = __expf(2.f * x);
    return 1.f - 2.f / (e + 1.f);
}

// async global->LDS, 16 bytes per lane (wave-uniform LDS base).
__device__ inline void gload16(const void* g, void* lds) {
    __builtin_amdgcn_global_load_lds(
        (const __attribute__((address_space(1))) unsigned int*)g,
        (__attribute__((address_space(3))) unsigned int*)lds, 16, 0, 0);
}

// ---------------------------------------------------------------------------
// f32 -> bf16 conversion with granule pre-swizzle (1024-col matrices).
// dst[row][seg][g] = cvt(src[row][seg][g ^ (row&7)])
__global__ void k_cvt_swz(const float* __restrict__ src, short* __restrict__ dst,
                          int granules) {
    int i = blockIdx.x * blockDim.x + threadIdx.x;
    if (i >= granules) return;
    int row = i >> 7, gi = i & 127;
    int seg = gi >> 3, g = gi & 7;
    const float* p = src + ((size_t)row << 10) + (seg << 6) + ((g ^ (row & 7)) << 3);
    float4 v0 = *(const float4*)p;
    float4 v1 = *(const float4*)(p + 4);
    *(short8*)&dst[(size_t)i << 3] = cvt8(v0, v1);
}

// ---------------------------------------------------------------------------
// Attention-score GEMM on pre-converted/pre-swizzled bf16 (128x128 tile,
// BK=64, global_load_lds staging). Fused tanh/Va epilogue -> atomic scores.
__global__ __launch_bounds__(256) void k_attn2(
    const short* __restrict__ Abf, const short* __restrict__ Bbf,
    const float* __restrict__ Uab, const float* __restrict__ Wab,
    const float* __restrict__ qp, const float* __restrict__ Va,
    float* __restrict__ scores) {
    __shared__ short As[128 * 64];
    __shared__ short Bs[128 * 64];
    const int t = threadIdx.x;
    const int l = t & 63, w = t >> 6;
    const int wm = w >> 1, wn = w & 1;
    const int lr = l & 15, lg = l >> 4;
    const int n0 = blockIdx.x * 128;
    const int r0 = blockIdx.y * 128;
    const int lrow8 = l >> 3, lgr = l & 7;

    f32x4 acc[4][4];
#pragma unroll
    for (int i = 0; i < 4; ++i)
#pragma unroll
        for (int j = 0; j < 4; ++j) { f32x4 z = {0.f, 0.f, 0.f, 0.f}; acc[i][j] = z; }

    for (int seg = 0; seg < 16; ++seg) {
#pragma unroll
        for (int i = 0; i < 4; ++i) {
            int arow = w * 32 + i * 8;  // wave-uniform
            gload16(Abf + (size_t)(r0 + arow + lrow8) * 1024 + seg * 64 + lgr * 8,
                    (void*)&As[arow * 64]);
            gload16(Bbf + (size_t)(n0 + arow + lrow8) * 1024 + seg * 64 + lgr * 8,
                    (void*)&Bs[arow * 64]);
        }
        __syncthreads();
#pragma unroll
        for (int kh = 0; kh < 2; ++kh) {
            short8 a[4], b[4];
#pragma unroll
            for (int i = 0; i < 4; ++i) {
                int ra = wm * 64 + i * 16 + lr;
                a[i] = *(const short8*)&As[ra * 64 + (((kh * 4 + lg) ^ (ra & 7)) << 3)];
                int rb = wn * 64 + i * 16 + lr;
                b[i] = *(const short8*)&Bs[rb * 64 + (((kh * 4 + lg) ^ (rb & 7)) << 3)];
            }
#pragma unroll
            for (int i = 0; i < 4; ++i)
#pragma unroll
                for (int j = 0; j < 4; ++j)
                    acc[i][j] = __builtin_amdgcn_mfma_f32_16x16x32_bf16(a[i], b[j], acc[i][j], 0, 0, 0);
        }
        __syncthreads();
    }

    const float* qpb = qp + blockIdx.y * 1024;
    float va[4], ub[4];
#pragma unroll
    for (int j = 0; j < 4; ++j) {
        int h = n0 + wn * 64 + j * 16 + lr;
        va[j] = Va[h];
        ub[j] = Uab[h] + Wab[h];
    }
#pragma unroll
    for (int i = 0; i < 4; ++i)
#pragma unroll
        for (int r = 0; r < 4; ++r) {
            int row = r0 + wm * 64 + i * 16 + lg * 4 + r;
            float s = 0.f;
#pragma unroll
            for (int j = 0; j < 4; ++j) {
                int h = n0 + wn * 64 + j * 16 + lr;
                s += va[j] * ftanh(acc[i][j][r] + qpb[h] + ub[j]);
            }
            s += __shfl_xor(s, 1);
            s += __shfl_xor(s, 2);
            s += __shfl_xor(s, 4);
            s += __shfl_xor(s, 8);
            if (lr == 0) atomicAdd(scores + row, s);
        }
}

// ---------------------------------------------------------------------------
// Fallback attention kernel (f32 in-kernel convert), used if ws too small.
__global__ __launch_bounds__(512, 2) void k_attn(
    const float* __restrict__ enc, const float* __restrict__ Ua,
    const float* __restrict__ Uab, const float* __restrict__ Wab,
    const float* __restrict__ qp, const float* __restrict__ Va,
    float* __restrict__ scores) {
    __shared__ short As[256 * 64];
    __shared__ short Bs[128 * 64];
    const int t = threadIdx.x;
    const int l = t & 63, w = t >> 6;
    const int wm = w >> 1, wn = w & 1;
    const int lr = l & 15, lg = l >> 4;
    const int n0 = blockIdx.x * 128;
    const int r0 = blockIdx.y * 256;

    f32x4 acc[4][4];
#pragma unroll
    for (int i = 0; i < 4; ++i)
#pragma unroll
        for (int j = 0; j < 4; ++j) { f32x4 z = {0.f, 0.f, 0.f, 0.f}; acc[i][j] = z; }

    auto stage = [&](int kt) {
#pragma unroll
        for (int i = 0; i < 4; ++i) {
            int s = t + 512 * i, row = s >> 3, ch = s & 7;
            const float* p = enc + (size_t)(r0 + row) * 1024 + kt + ch * 8;
            *(short8*)&As[row * 64 + ((ch ^ (row & 7)) << 3)] =
                cvt8(*(const float4*)p, *(const float4*)(p + 4));
        }
#pragma unroll
        for (int i = 0; i < 2; ++i) {
            int s = t + 512 * i, row = s >> 3, ch = s & 7;
            const float* p = Ua + (size_t)(n0 + row) * 1024 + kt + ch * 8;
            *(short8*)&Bs[row * 64 + ((ch ^ (row & 7)) << 3)] =
                cvt8(*(const float4*)p, *(const float4*)(p + 4));
        }
    };
    auto compute = [&]() {
#pragma unroll
        for (int kh = 0; kh < 2; ++kh) {
            short8 a[4], b[4];
#pragma unroll
            for (int i = 0; i < 4; ++i) {
                int row = wm * 64 + i * 16 + lr;
                a[i] = *(short8*)&As[row * 64 + ((((kh << 2) | lg) ^ (row & 7)) << 3)];
            }
#pragma unroll
            for (int j = 0; j < 4; ++j) {
                int row = wn * 64 + j * 16 + lr;
                b[j] = *(short8*)&Bs[row * 64 + ((((kh << 2) | lg) ^ (row & 7)) << 3)];
            }
#pragma unroll
            for (int i = 0; i < 4; ++i)
#pragma unroll
                for (int j = 0; j < 4; ++j)
                    acc[i][j] = __builtin_amdgcn_mfma_f32_16x16x32_bf16(a[i], b[j], acc[i][j], 0, 0, 0);
        }
    };

    for (int kt = 0; kt < 1024; kt += 64) {
        stage(kt);
        __syncthreads();
        compute();
        __syncthreads();
    }

    float va[4], ub[4];
#pragma unroll
    for (int j = 0; j < 4; ++j) {
        int h = n0 + wn * 64 + j * 16 + lr;
        va[j] = Va[h];
        ub[j] = Uab[h] + Wab[h];
    }
#pragma unroll
    for (int i = 0; i < 4; ++i)
#pragma unroll
        for (int r = 0; r < 4; ++r) {
            int row = r0 + wm * 64 + i * 16 + lg * 4 + r;
            const float* qpb = qp + (row >> 7) * 1024;
            float s = 0.f;
#pragma unroll
            for (int j = 0; j < 4; ++j) {
                int h = n0 + wn * 64 + j * 16 + lr;
                s += va[j] * ftanh(acc[i][j][r] + qpb[h] + ub[j]);
            }
            s += __shfl_xor(s, 1);
            s += __shfl_xor(s, 2);
            s += __shfl_xor(s, 4);
            s += __shfl_xor(s, 8);
            if (lr == 0) atomicAdd(scores + row, s);
        }
}

// ---------------------------------------------------------------------------
// Skinny split-K GEMM: C(64 x N) += A(64 x Ktot) @ [B0|B1](N x Ktot)^T.
// Tile 64x64, Kblk per ky; 256 thr = 4 waves (2M x 2N), wave tile 32x32.
// C must be pre-initialized (zero or bias); epilogue is atomicAdd.
__global__ __launch_bounds__(256) void k_sgemm(
    const float* __restrict__ A, int lda,
    const float* __restrict__ B0, int ldb0,
    const float* __restrict__ B1, int ldb1, int kyB1,
    float* __restrict__ C, int ldc, int Kblk) {
    __shared__ short As[64 * 64];
    __shared__ short Bs[64 * 64];
    const int t = threadIdx.x;
    const int l = t & 63, w = t >> 6;
    const int wm = w >> 1, wn = w & 1;
    const int lr = l & 15, lg = l >> 4;
    const int n0 = blockIdx.x * 64;
    const int ky = blockIdx.y;

    const float* Ab = A + (size_t)ky * Kblk;
    const float* Bb;
    int ldb;
    if (ky < kyB1) { Bb = B0 + (size_t)ky * Kblk; ldb = ldb0; }
    else           { Bb = B1 + (size_t)(ky - kyB1) * Kblk; ldb = ldb1; }

    f32x4 acc[2][2];
#pragma unroll
    for (int i = 0; i < 2; ++i)
#pragma unroll
        for (int j = 0; j < 2; ++j) { f32x4 z = {0.f, 0.f, 0.f, 0.f}; acc[i][j] = z; }

    for (int kt = 0; kt < Kblk; kt += 64) {
#pragma unroll
        for (int i = 0; i < 2; ++i) {
            int s = t + 256 * i, row = s >> 3, ch = s & 7;
            const float* p = Ab + (size_t)row * lda + kt + ch * 8;
            *(short8*)&As[row * 64 + ((ch ^ (row & 7)) << 3)] =
                cvt8(*(const float4*)p, *(const float4*)(p + 4));
            const float* q = Bb + (size_t)(n0 + row) * ldb + kt + ch * 8;
            *(short8*)&Bs[row * 64 + ((ch ^ (row & 7)) << 3)] =
                cvt8(*(const float4*)q, *(const float4*)(q + 4));
        }
        __syncthreads();
#pragma unroll
        for (int kh = 0; kh < 2; ++kh) {
            short8 a[2], b[2];
#pragma unroll
            for (int i = 0; i < 2; ++i) {
                int ra = wm * 32 + i * 16 + lr;
                a[i] = *(const short8*)&As[ra * 64 + (((kh * 4 + lg) ^ (ra & 7)) << 3)];
                int rb = wn * 32 + i * 16 + lr;
                b[i] = *(const short8*)&Bs[rb * 64 + (((kh * 4 + lg) ^ (rb & 7)) << 3)];
            }
#pragma unroll
            for (int i = 0; i < 2; ++i)
#pragma unroll
                for (int j = 0; j < 2; ++j)
                    acc[i][j] = __builtin_amdgcn_mfma_f32_16x16x32_bf16(a[i], b[j], acc[i][j], 0, 0, 0);
        }
        __syncthreads();
    }

#pragma unroll
    for (int i = 0; i < 2; ++i)
#pragma unroll
        for (int j = 0; j < 2; ++j)
#pragma unroll
            for (int r = 0; r < 4; ++r) {
                int R = wm * 32 + i * 16 + lg * 4 + r;
                int c = n0 + wn * 32 + j * 16 + lr;
                atomicAdd(&C[(size_t)R * ldc + c], acc[i][j][r]);
            }
}

// ---------------------------------------------------------------------------
// broadcast out_b into all 64 logits rows (pre-init for atomic GEMM)
__global__ void k_biasinit(const float* __restrict__ ob, float* __restrict__ logits) {
    int i = blockIdx.x * blockDim.x + threadIdx.x;  // over 512000 float4
    if (i >= 512000) return;
    int c4 = i - (i / 8000) * 8000;
    ((float4*)logits)[i] = ((const float4*)ob)[c4];
}

__global__ void k_gather(const int* __restrict__ idx, const float* __restrict__ emb,
                         const float* __restrict__ h0, float* __restrict__ xcat) {
    int b = blockIdx.x;
    int row = idx[b];
    const float4* se = (const float4*)(emb + (size_t)row * 1024);
    const float4* sh = (const float4*)(h0 + (size_t)b * 1024);
    float4* d = (float4*)(xcat + (size_t)b * 3072);
    for (int i = threadIdx.x; i < 256; i += blockDim.x) {
        d[i] = se[i];
        d[512 + i] = sh[i];
    }
}

__global__ void k_softmax(const float* __restrict__ scores, float* __restrict__ wout) {
    int b = blockIdx.x;
    int s = threadIdx.x;  // 128
    __shared__ float buf[128];
    float v = scores[b * 128 + s];
    buf[s] = v;
    __syncthreads();
    for (int off = 64; off > 0; off >>= 1) {
        if (s < off) buf[s] = fmaxf(buf[s], buf[s + off]);
        __syncthreads();
    }
    float m = buf[0];
    __syncthreads();
    float e = expf(v - m);
    buf[s] = e;
    __syncthreads();
    for (int off = 64; off > 0; off >>= 1) {
        if (s < off) buf[s] += buf[s + off];
        __syncthreads();
    }
    float sum = buf[0];
    wout[b * 128 + s] = e / sum;
}

// context -> xcat[:,1024:2048]; grid (4 h-chunks, 64 batches)
__global__ void k_context(const float* __restrict__ enc, const float* __restrict__ w,
                          float* __restrict__ xcat) {
    int b = blockIdx.y;
    int t = threadIdx.x;
    int h = blockIdx.x * 256 + t;
    __shared__ float wsb[128];
    if (t < 128) wsb[t] = w[b * 128 + t];
    __syncthreads();
    float acc = 0.f;
#pragma unroll 4
    for (int s = 0; s < 128; ++s)
        acc += wsb[s] * enc[((size_t)b * 128 + s) * 1024 + h];
    xcat[(size_t)b * 3072 + 1024 + h] = acc;
}

__global__ void k_lstm(const float* __restrict__ gates, const float* __restrict__ c0,
                       const float* __restrict__ b_ih, const float* __restrict__ b_hh,
                       float* __restrict__ h1, float* __restrict__ c1) {
    int idx = blockIdx.x * blockDim.x + threadIdx.x;  // 65536
    int b = idx >> 10, h = idx & 1023;
    const float* g = gates + (size_t)b * 4096;
    float iv = g[h] + b_ih[h] + b_hh[h];
    float fv = g[1024 + h] + b_ih[1024 + h] + b_hh[1024 + h];
    float gv = g[2048 + h] + b_ih[2048 + h] + b_hh[2048 + h];
    float ov = g[3072 + h] + b_ih[3072 + h] + b_hh[3072 + h];
    float si = 1.f / (1.f + expf(-iv));
    float sf = 1.f / (1.f + expf(-fv));
    float so = 1.f / (1.f + expf(-ov));
    float tg = tanhf(gv);
    float cc = sf * c0[idx] + si * tg;
    float hh = so * tanhf(cc);
    c1[idx] = cc;
    h1[idx] = hh;
}

// ---------------------------------------------------------------------------
extern "C" void kernel_launch(void* const* d_in, const int* in_sizes, int n_in,
                              void* d_out, int out_size, void* d_ws, size_t ws_size,
                              hipStream_t stream) {
    const int* idx = (const int*)d_in[0];
    const float* hidden = (const float*)d_in[1];
    const float* cell = (const float*)d_in[2];
    const float* enc = (const float*)d_in[3];
    const float* emb = (const float*)d_in[4];
    const float* Wa_w = (const float*)d_in[5];
    const float* Wa_b = (const float*)d_in[6];
    const float* Ua_w = (const float*)d_in[7];
    const float* Ua_b = (const float*)d_in[8];
    const float* Va_w = (const float*)d_in[9];
    // d_in[10] Va_b unused: softmax shift-invariant
    const float* W_ih = (const float*)d_in[11];
    const float* W_hh = (const float*)d_in[12];
    const float* b_ih = (const float*)d_in[13];
    const float* b_hh = (const float*)d_in[14];
    const float* out_w = (const float*)d_in[15];
    const float* out_b = (const float*)d_in[16];

    float* out = (float*)d_out;
    float* logits = out;                             // 64*32000
    float* h1 = out + 2048000;                       // 64*1024
    float* c1 = out + 2048000 + 65536;               // 64*1024
    float* wts = out + 2048000 + 65536 + 65536;      // 64*128

    float* ws = (float*)d_ws;
    float* qp = ws;                    // 65536
    float* scores = ws + 65536;        // 8192
    float* xcat = ws + 65536 + 8192;   // 64*3072 = 196608
    float* gates = xcat + 196608;      // 64*4096 = 262144
    short* enc_bf = (short*)(ws + 532480);           // 8192*1024 bf16
    short* ua_bf  = enc_bf + 8192 * 1024;            // 1024*1024 bf16
    const size_t ws_need = 532480u * 4u + (8192u * 1024u + 1024u * 1024u) * 2u;
    const bool big_ws = ws_size >= ws_need;

    hipMemsetAsync(qp, 0, (65536 + 8192) * sizeof(float), stream);  // qp + scores
    hipMemsetAsync(gates, 0, 262144 * sizeof(float), stream);

    if (big_ws) {
        k_cvt_swz<<<4096, 256, 0, stream>>>(enc, enc_bf, 8192 * 128);
        k_cvt_swz<<<512, 256, 0, stream>>>(Ua_w, ua_bf, 1024 * 128);
    }
    k_gather<<<64, 256, 0, stream>>>(idx, emb, hidden, xcat);
    // qp = h0 @ Wa^T (Wa_b folded into attn epilogue), split-K x8
    k_sgemm<<<dim3(16, 8), 256, 0, stream>>>(hidden, 1024, Wa_w, 1024,
                                             nullptr, 0, 99, qp, 1024, 128);
    if (big_ws)
        k_attn2<<<dim3(8, 64), 256, 0, stream>>>(enc_bf, ua_bf, Ua_b, Wa_b, qp, Va_w, scores);
    else
        k_attn<<<dim3(8, 32), 512, 0, stream>>>(enc, Ua_w, Ua_b, Wa_b, qp, Va_w, scores);
    k_softmax<<<64, 128, 0, stream>>>(scores, wts);
    k_context<<<dim3(4, 64), 256, 0, stream>>>(enc, wts, xcat);
    // gates = xcat @ [W_ih | W_hh]^T, split-K x12 (Kblk=256; ky<8 -> W_ih)
    k_sgemm<<<dim3(64, 12), 256, 0, stream>>>(xcat, 3072, W_ih, 2048,
                                              W_hh, 1024, 8, gates, 4096, 256);
    k_lstm<<<256, 256, 0, stream>>>(gates, cell, b_ih, b_hh, h1, c1);
    // logits = out_b (init) + h1 @ out_w^T, split-K x4
    k_biasinit<<<2000, 256, 0, stream>>>(out_b, logits);
    k_sgemm<<<dim3(500, 4), 256, 0, stream>>>(h1, 1024, out_w, 1024,
                                              nullptr, 0, 99, logits, 32000, 256);
}

// Round 7
// 142.945 us; speedup vs baseline: 2.0549x; 1.0272x over previous
//
#include <hip/hip_runtime.h>
#include <hip/hip_bf16.h>

using short8 = __attribute__((ext_vector_type(8))) short;
using f32x4  = __attribute__((ext_vector_type(4))) float;

// packed f32x2 -> bf16x2 (RNE) via v_cvt_pk_bf16_f32
__device__ inline unsigned pk2(float lo, float hi) {
    __hip_bfloat162 h = __float22bfloat162_rn(float2{lo, hi});
    return *reinterpret_cast<unsigned*>(&h);
}
__device__ inline short8 cvt8(float4 a, float4 b) {
    union { unsigned u[4]; short8 s; } r;
    r.u[0] = pk2(a.x, a.y); r.u[1] = pk2(a.z, a.w);
    r.u[2] = pk2(b.x, b.y); r.u[3] = pk2(b.z, b.w);
    return r.s;
}
// fast tanh: 1 - 2/(e^{2x}+1)
__device__ inline float ftanh(float x) {
    float e = __expf(2.f * x);
    return 1.f - 2.f / (e + 1.f);
}

// async global->LDS, 16 bytes per lane (wave-uniform LDS base).
__device__ inline void gload16(const void* g, void* lds) {
    __builtin_amdgcn_global_load_lds(
        (const __attribute__((address_space(1))) unsigned int*)g,
        (__attribute__((address_space(3))) unsigned int*)lds, 16, 0, 0);
}

// ---------------------------------------------------------------------------
// grid-strided zero of n float4s (replaces pathologically slow rocclr fill)
__global__ void k_zero(float4* __restrict__ p, int n) {
    for (int i = blockIdx.x * blockDim.x + threadIdx.x; i < n;
         i += gridDim.x * blockDim.x) {
        float4 z = {0.f, 0.f, 0.f, 0.f};
        p[i] = z;
    }
}

// ---------------------------------------------------------------------------
// f32 -> bf16 conversion with granule pre-swizzle (1024-col matrices).
// dst[row][seg][g] = cvt(src[row][seg][g ^ (row&7)])
__global__ void k_cvt_swz(const float* __restrict__ src, short* __restrict__ dst,
                          int granules) {
    int i = blockIdx.x * blockDim.x + threadIdx.x;
    if (i >= granules) return;
    int row = i >> 7, gi = i & 127;
    int seg = gi >> 3, g = gi & 7;
    const float* p = src + ((size_t)row << 10) + (seg << 6) + ((g ^ (row & 7)) << 3);
    float4 v0 = *(const float4*)p;
    float4 v1 = *(const float4*)(p + 4);
    *(short8*)&dst[(size_t)i << 3] = cvt8(v0, v1);
}

// ---------------------------------------------------------------------------
// Attention-score GEMM on pre-converted/pre-swizzled bf16 (128x128 tile,
// BK=64, global_load_lds staging). Fused tanh/Va epilogue -> atomic scores.
__global__ __launch_bounds__(256) void k_attn2(
    const short* __restrict__ Abf, const short* __restrict__ Bbf,
    const float* __restrict__ Uab, const float* __restrict__ Wab,
    const float* __restrict__ qp, const float* __restrict__ Va,
    float* __restrict__ scores) {
    __shared__ short As[128 * 64];
    __shared__ short Bs[128 * 64];
    const int t = threadIdx.x;
    const int l = t & 63, w = t >> 6;
    const int wm = w >> 1, wn = w & 1;
    const int lr = l & 15, lg = l >> 4;
    const int n0 = blockIdx.x * 128;
    const int r0 = blockIdx.y * 128;
    const int lrow8 = l >> 3, lgr = l & 7;

    f32x4 acc[4][4];
#pragma unroll
    for (int i = 0; i < 4; ++i)
#pragma unroll
        for (int j = 0; j < 4; ++j) { f32x4 z = {0.f, 0.f, 0.f, 0.f}; acc[i][j] = z; }

    for (int seg = 0; seg < 16; ++seg) {
#pragma unroll
        for (int i = 0; i < 4; ++i) {
            int arow = w * 32 + i * 8;  // wave-uniform
            gload16(Abf + (size_t)(r0 + arow + lrow8) * 1024 + seg * 64 + lgr * 8,
                    (void*)&As[arow * 64]);
            gload16(Bbf + (size_t)(n0 + arow + lrow8) * 1024 + seg * 64 + lgr * 8,
                    (void*)&Bs[arow * 64]);
        }
        __syncthreads();
#pragma unroll
        for (int kh = 0; kh < 2; ++kh) {
            short8 a[4], b[4];
#pragma unroll
            for (int i = 0; i < 4; ++i) {
                int ra = wm * 64 + i * 16 + lr;
                a[i] = *(const short8*)&As[ra * 64 + (((kh * 4 + lg) ^ (ra & 7)) << 3)];
                int rb = wn * 64 + i * 16 + lr;
                b[i] = *(const short8*)&Bs[rb * 64 + (((kh * 4 + lg) ^ (rb & 7)) << 3)];
            }
#pragma unroll
            for (int i = 0; i < 4; ++i)
#pragma unroll
                for (int j = 0; j < 4; ++j)
                    acc[i][j] = __builtin_amdgcn_mfma_f32_16x16x32_bf16(a[i], b[j], acc[i][j], 0, 0, 0);
        }
        __syncthreads();
    }

    const float* qpb = qp + blockIdx.y * 1024;
    float va[4], ub[4];
#pragma unroll
    for (int j = 0; j < 4; ++j) {
        int h = n0 + wn * 64 + j * 16 + lr;
        va[j] = Va[h];
        ub[j] = Uab[h] + Wab[h];
    }
#pragma unroll
    for (int i = 0; i < 4; ++i)
#pragma unroll
        for (int r = 0; r < 4; ++r) {
            int row = r0 + wm * 64 + i * 16 + lg * 4 + r;
            float s = 0.f;
#pragma unroll
            for (int j = 0; j < 4; ++j) {
                int h = n0 + wn * 64 + j * 16 + lr;
                s += va[j] * ftanh(acc[i][j][r] + qpb[h] + ub[j]);
            }
            s += __shfl_xor(s, 1);
            s += __shfl_xor(s, 2);
            s += __shfl_xor(s, 4);
            s += __shfl_xor(s, 8);
            if (lr == 0) atomicAdd(scores + row, s);
        }
}

// ---------------------------------------------------------------------------
// Fallback attention kernel (f32 in-kernel convert), used if ws too small.
__global__ __launch_bounds__(512, 2) void k_attn(
    const float* __restrict__ enc, const float* __restrict__ Ua,
    const float* __restrict__ Uab, const float* __restrict__ Wab,
    const float* __restrict__ qp, const float* __restrict__ Va,
    float* __restrict__ scores) {
    __shared__ short As[256 * 64];
    __shared__ short Bs[128 * 64];
    const int t = threadIdx.x;
    const int l = t & 63, w = t >> 6;
    const int wm = w >> 1, wn = w & 1;
    const int lr = l & 15, lg = l >> 4;
    const int n0 = blockIdx.x * 128;
    const int r0 = blockIdx.y * 256;

    f32x4 acc[4][4];
#pragma unroll
    for (int i = 0; i < 4; ++i)
#pragma unroll
        for (int j = 0; j < 4; ++j) { f32x4 z = {0.f, 0.f, 0.f, 0.f}; acc[i][j] = z; }

    auto stage = [&](int kt) {
#pragma unroll
        for (int i = 0; i < 4; ++i) {
            int s = t + 512 * i, row = s >> 3, ch = s & 7;
            const float* p = enc + (size_t)(r0 + row) * 1024 + kt + ch * 8;
            *(short8*)&As[row * 64 + ((ch ^ (row & 7)) << 3)] =
                cvt8(*(const float4*)p, *(const float4*)(p + 4));
        }
#pragma unroll
        for (int i = 0; i < 2; ++i) {
            int s = t + 512 * i, row = s >> 3, ch = s & 7;
            const float* p = Ua + (size_t)(n0 + row) * 1024 + kt + ch * 8;
            *(short8*)&Bs[row * 64 + ((ch ^ (row & 7)) << 3)] =
                cvt8(*(const float4*)p, *(const float4*)(p + 4));
        }
    };
    auto compute = [&]() {
#pragma unroll
        for (int kh = 0; kh < 2; ++kh) {
            short8 a[4], b[4];
#pragma unroll
            for (int i = 0; i < 4; ++i) {
                int row = wm * 64 + i * 16 + lr;
                a[i] = *(short8*)&As[row * 64 + ((((kh << 2) | lg) ^ (row & 7)) << 3)];
            }
#pragma unroll
            for (int j = 0; j < 4; ++j) {
                int row = wn * 64 + j * 16 + lr;
                b[j] = *(short8*)&Bs[row * 64 + ((((kh << 2) | lg) ^ (row & 7)) << 3)];
            }
#pragma unroll
            for (int i = 0; i < 4; ++i)
#pragma unroll
                for (int j = 0; j < 4; ++j)
                    acc[i][j] = __builtin_amdgcn_mfma_f32_16x16x32_bf16(a[i], b[j], acc[i][j], 0, 0, 0);
        }
    };

    for (int kt = 0; kt < 1024; kt += 64) {
        stage(kt);
        __syncthreads();
        compute();
        __syncthreads();
    }

    float va[4], ub[4];
#pragma unroll
    for (int j = 0; j < 4; ++j) {
        int h = n0 + wn * 64 + j * 16 + lr;
        va[j] = Va[h];
        ub[j] = Uab[h] + Wab[h];
    }
#pragma unroll
    for (int i = 0; i < 4; ++i)
#pragma unroll
        for (int r = 0; r < 4; ++r) {
            int row = r0 + wm * 64 + i * 16 + lg * 4 + r;
            const float* qpb = qp + (row >> 7) * 1024;
            float s = 0.f;
#pragma unroll
            for (int j = 0; j < 4; ++j) {
                int h = n0 + wn * 64 + j * 16 + lr;
                s += va[j] * ftanh(acc[i][j][r] + qpb[h] + ub[j]);
            }
            s += __shfl_xor(s, 1);
            s += __shfl_xor(s, 2);
            s += __shfl_xor(s, 4);
            s += __shfl_xor(s, 8);
            if (lr == 0) atomicAdd(scores + row, s);
        }
}

// ---------------------------------------------------------------------------
// Skinny split-K GEMM: C(64 x N) += A(64 x Ktot) @ [B0|B1](N x Ktot)^T.
// Tile 64x64, Kblk per ky; 256 thr = 4 waves (2M x 2N), wave tile 32x32.
// C must be pre-initialized (zero or bias); epilogue is atomicAdd.
__global__ __launch_bounds__(256) void k_sgemm(
    const float* __restrict__ A, int lda,
    const float* __restrict__ B0, int ldb0,
    const float* __restrict__ B1, int ldb1, int kyB1,
    float* __restrict__ C, int ldc, int Kblk) {
    __shared__ short As[64 * 64];
    __shared__ short Bs[64 * 64];
    const int t = threadIdx.x;
    const int l = t & 63, w = t >> 6;
    const int wm = w >> 1, wn = w & 1;
    const int lr = l & 15, lg = l >> 4;
    const int n0 = blockIdx.x * 64;
    const int ky = blockIdx.y;

    const float* Ab = A + (size_t)ky * Kblk;
    const float* Bb;
    int ldb;
    if (ky < kyB1) { Bb = B0 + (size_t)ky * Kblk; ldb = ldb0; }
    else           { Bb = B1 + (size_t)(ky - kyB1) * Kblk; ldb = ldb1; }

    f32x4 acc[2][2];
#pragma unroll
    for (int i = 0; i < 2; ++i)
#pragma unroll
        for (int j = 0; j < 2; ++j) { f32x4 z = {0.f, 0.f, 0.f, 0.f}; acc[i][j] = z; }

    for (int kt = 0; kt < Kblk; kt += 64) {
#pragma unroll
        for (int i = 0; i < 2; ++i) {
            int s = t + 256 * i, row = s >> 3, ch = s & 7;
            const float* p = Ab + (size_t)row * lda + kt + ch * 8;
            *(short8*)&As[row * 64 + ((ch ^ (row & 7)) << 3)] =
                cvt8(*(const float4*)p, *(const float4*)(p + 4));
            const float* q = Bb + (size_t)(n0 + row) * ldb + kt + ch * 8;
            *(short8*)&Bs[row * 64 + ((ch ^ (row & 7)) << 3)] =
                cvt8(*(const float4*)q, *(const float4*)(q + 4));
        }
        __syncthreads();
#pragma unroll
        for (int kh = 0; kh < 2; ++kh) {
            short8 a[2], b[2];
#pragma unroll
            for (int i = 0; i < 2; ++i) {
                int ra = wm * 32 + i * 16 + lr;
                a[i] = *(const short8*)&As[ra * 64 + (((kh * 4 + lg) ^ (ra & 7)) << 3)];
                int rb = wn * 32 + i * 16 + lr;
                b[i] = *(const short8*)&Bs[rb * 64 + (((kh * 4 + lg) ^ (rb & 7)) << 3)];
            }
#pragma unroll
            for (int i = 0; i < 2; ++i)
#pragma unroll
                for (int j = 0; j < 2; ++j)
                    acc[i][j] = __builtin_amdgcn_mfma_f32_16x16x32_bf16(a[i], b[j], acc[i][j], 0, 0, 0);
        }
        __syncthreads();
    }

#pragma unroll
    for (int i = 0; i < 2; ++i)
#pragma unroll
        for (int j = 0; j < 2; ++j)
#pragma unroll
            for (int r = 0; r < 4; ++r) {
                int R = wm * 32 + i * 16 + lg * 4 + r;
                int c = n0 + wn * 32 + j * 16 + lr;
                atomicAdd(&C[(size_t)R * ldc + c], acc[i][j][r]);
            }
}

// ---------------------------------------------------------------------------
// broadcast out_b into all 64 logits rows (pre-init for atomic GEMM)
__global__ void k_biasinit(const float* __restrict__ ob, float* __restrict__ logits) {
    int i = blockIdx.x * blockDim.x + threadIdx.x;  // over 512000 float4
    if (i >= 512000) return;
    int c4 = i - (i / 8000) * 8000;
    ((float4*)logits)[i] = ((const float4*)ob)[c4];
}

__global__ void k_gather(const int* __restrict__ idx, const float* __restrict__ emb,
                         const float* __restrict__ h0, float* __restrict__ xcat) {
    int b = blockIdx.x;
    int row = idx[b];
    const float4* se = (const float4*)(emb + (size_t)row * 1024);
    const float4* sh = (const float4*)(h0 + (size_t)b * 1024);
    float4* d = (float4*)(xcat + (size_t)b * 3072);
    for (int i = threadIdx.x; i < 256; i += blockDim.x) {
        d[i] = se[i];
        d[512 + i] = sh[i];
    }
}

__global__ void k_softmax(const float* __restrict__ scores, float* __restrict__ wout) {
    int b = blockIdx.x;
    int s = threadIdx.x;  // 128
    __shared__ float buf[128];
    float v = scores[b * 128 + s];
    buf[s] = v;
    __syncthreads();
    for (int off = 64; off > 0; off >>= 1) {
        if (s < off) buf[s] = fmaxf(buf[s], buf[s + off]);
        __syncthreads();
    }
    float m = buf[0];
    __syncthreads();
    float e = expf(v - m);
    buf[s] = e;
    __syncthreads();
    for (int off = 64; off > 0; off >>= 1) {
        if (s < off) buf[s] += buf[s + off];
        __syncthreads();
    }
    float sum = buf[0];
    wout[b * 128 + s] = e / sum;
}

// context -> xcat[:,1024:2048]; grid (4 h-chunks, 64 batches)
__global__ void k_context(const float* __restrict__ enc, const float* __restrict__ w,
                          float* __restrict__ xcat) {
    int b = blockIdx.y;
    int t = threadIdx.x;
    int h = blockIdx.x * 256 + t;
    __shared__ float wsb[128];
    if (t < 128) wsb[t] = w[b * 128 + t];
    __syncthreads();
    float acc = 0.f;
#pragma unroll 4
    for (int s = 0; s < 128; ++s)
        acc += wsb[s] * enc[((size_t)b * 128 + s) * 1024 + h];
    xcat[(size_t)b * 3072 + 1024 + h] = acc;
}

__global__ void k_lstm(const float* __restrict__ gates, const float* __restrict__ c0,
                       const float* __restrict__ b_ih, const float* __restrict__ b_hh,
                       float* __restrict__ h1, float* __restrict__ c1) {
    int idx = blockIdx.x * blockDim.x + threadIdx.x;  // 65536
    int b = idx >> 10, h = idx & 1023;
    const float* g = gates + (size_t)b * 4096;
    float iv = g[h] + b_ih[h] + b_hh[h];
    float fv = g[1024 + h] + b_ih[1024 + h] + b_hh[1024 + h];
    float gv = g[2048 + h] + b_ih[2048 + h] + b_hh[2048 + h];
    float ov = g[3072 + h] + b_ih[3072 + h] + b_hh[3072 + h];
    float si = 1.f / (1.f + expf(-iv));
    float sf = 1.f / (1.f + expf(-fv));
    float so = 1.f / (1.f + expf(-ov));
    float tg = tanhf(gv);
    float cc = sf * c0[idx] + si * tg;
    float hh = so * tanhf(cc);
    c1[idx] = cc;
    h1[idx] = hh;
}

// ---------------------------------------------------------------------------
extern "C" void kernel_launch(void* const* d_in, const int* in_sizes, int n_in,
                              void* d_out, int out_size, void* d_ws, size_t ws_size,
                              hipStream_t stream) {
    const int* idx = (const int*)d_in[0];
    const float* hidden = (const float*)d_in[1];
    const float* cell = (const float*)d_in[2];
    const float* enc = (const float*)d_in[3];
    const float* emb = (const float*)d_in[4];
    const float* Wa_w = (const float*)d_in[5];
    const float* Wa_b = (const float*)d_in[6];
    const float* Ua_w = (const float*)d_in[7];
    const float* Ua_b = (const float*)d_in[8];
    const float* Va_w = (const float*)d_in[9];
    // d_in[10] Va_b unused: softmax shift-invariant
    const float* W_ih = (const float*)d_in[11];
    const float* W_hh = (const float*)d_in[12];
    const float* b_ih = (const float*)d_in[13];
    const float* b_hh = (const float*)d_in[14];
    const float* out_w = (const float*)d_in[15];
    const float* out_b = (const float*)d_in[16];

    float* out = (float*)d_out;
    float* logits = out;                             // 64*32000
    float* h1 = out + 2048000;                       // 64*1024
    float* c1 = out + 2048000 + 65536;               // 64*1024
    float* wts = out + 2048000 + 65536 + 65536;      // 64*128

    // ws layout: [qp | scores | gates] contiguous (zeroed together), then xcat
    float* ws = (float*)d_ws;
    float* qp = ws;                      // 65536
    float* scores = ws + 65536;          // 8192
    float* gates = ws + 73728;           // 262144
    float* xcat = ws + 335872;           // 196608  (total f32 scratch 532480)
    short* enc_bf = (short*)(ws + 532480);           // 8192*1024 bf16
    short* ua_bf  = enc_bf + 8192 * 1024;            // 1024*1024 bf16
    const size_t ws_need = 532480u * 4u + (8192u * 1024u + 1024u * 1024u) * 2u;
    const bool big_ws = ws_size >= ws_need;

    // zero qp+scores+gates (335872 floats = 83968 float4) with our own kernel;
    // rocclr fillBuffer was measured at 14 GB/s / ~75 us per replay.
    k_zero<<<192, 256, 0, stream>>>((float4*)ws, 83968);

    if (big_ws) {
        k_cvt_swz<<<4096, 256, 0, stream>>>(enc, enc_bf, 8192 * 128);
        k_cvt_swz<<<512, 256, 0, stream>>>(Ua_w, ua_bf, 1024 * 128);
    }
    k_gather<<<64, 256, 0, stream>>>(idx, emb, hidden, xcat);
    // qp = h0 @ Wa^T (Wa_b folded into attn epilogue), split-K x8
    k_sgemm<<<dim3(16, 8), 256, 0, stream>>>(hidden, 1024, Wa_w, 1024,
                                             nullptr, 0, 99, qp, 1024, 128);
    if (big_ws)
        k_attn2<<<dim3(8, 64), 256, 0, stream>>>(enc_bf, ua_bf, Ua_b, Wa_b, qp, Va_w, scores);
    else
        k_attn<<<dim3(8, 32), 512, 0, stream>>>(enc, Ua_w, Ua_b, Wa_b, qp, Va_w, scores);
    k_softmax<<<64, 128, 0, stream>>>(scores, wts);
    k_context<<<dim3(4, 64), 256, 0, stream>>>(enc, wts, xcat);
    // gates = xcat @ [W_ih | W_hh]^T, split-K x12 (Kblk=256; ky<8 -> W_ih)
    k_sgemm<<<dim3(64, 12), 256, 0, stream>>>(xcat, 3072, W_ih, 2048,
                                              W_hh, 1024, 8, gates, 4096, 256);
    k_lstm<<<256, 256, 0, stream>>>(gates, cell, b_ih, b_hh, h1, c1);
    // logits = out_b (init) + h1 @ out_w^T, split-K x4
    k_biasinit<<<2000, 256, 0, stream>>>(out_b, logits);
    k_sgemm<<<dim3(500, 4), 256, 0, stream>>>(h1, 1024, out_w, 1024,
                                              nullptr, 0, 99, logits, 32000, 256);
}

// Round 8
// 135.008 us; speedup vs baseline: 2.1757x; 1.0588x over previous
//
#include <hip/hip_runtime.h>
#include <hip/hip_bf16.h>

using short8 = __attribute__((ext_vector_type(8))) short;
using f32x4  = __attribute__((ext_vector_type(4))) float;

__device__ inline unsigned pk2(float lo, float hi) {
    __hip_bfloat162 h = __float22bfloat162_rn(float2{lo, hi});
    return *reinterpret_cast<unsigned*>(&h);
}
__device__ inline short8 cvt8(float4 a, float4 b) {
    union { unsigned u[4]; short8 s; } r;
    r.u[0] = pk2(a.x, a.y); r.u[1] = pk2(a.z, a.w);
    r.u[2] = pk2(b.x, b.y); r.u[3] = pk2(b.z, b.w);
    return r.s;
}
__device__ inline float ftanh(float x) {
    float e = __expf(2.f * x);
    return 1.f - 2.f / (e + 1.f);
}
__device__ inline void gload16(const void* g, void* lds) {
    __builtin_amdgcn_global_load_lds(
        (const __attribute__((address_space(1))) unsigned int*)g,
        (__attribute__((address_space(3))) unsigned int*)lds, 16, 0, 0);
}

// ---------------------------------------------------------------------------
// Fused init: [0,83968) zero qp|scores|gates; [83968,595968) logits=bias;
// [595968,645120) xcat gather (emb row + h0). All float4 writes.
__global__ void k_init(const float* __restrict__ ob, float* __restrict__ logits,
                       const int* __restrict__ idx, const float* __restrict__ emb,
                       const float* __restrict__ h0, float* __restrict__ xcat,
                       float4* __restrict__ wsz) {
    int i = blockIdx.x * blockDim.x + threadIdx.x;
    if (i < 83968) {
        float4 z = {0.f, 0.f, 0.f, 0.f};
        wsz[i] = z;
    } else if (i < 595968) {
        int j = i - 83968;
        int c4 = j - (j / 8000) * 8000;
        ((float4*)logits)[j] = ((const float4*)ob)[c4];
    } else if (i < 645120) {
        int j = i - 595968;
        int b = j / 768, q = j - b * 768;
        if (q < 256)
            ((float4*)(xcat + (size_t)b * 3072))[q] =
                ((const float4*)(emb + (size_t)idx[b] * 1024))[q];
        else if (q >= 512)
            ((float4*)(xcat + (size_t)b * 3072))[q] =
                ((const float4*)(h0 + (size_t)b * 1024))[q - 512];
    }
}

// ---------------------------------------------------------------------------
// f32 -> bf16 with granule pre-swizzle; rows 0..8191 from enc, 8192+ from Ua.
// dst[row][seg][g] = cvt(src[row][seg][g ^ (row&7)])
__global__ void k_cvt_swz(const float* __restrict__ enc, const float* __restrict__ Ua,
                          short* __restrict__ dst) {
    int i = blockIdx.x * blockDim.x + threadIdx.x;  // 9216*128 granules
    if (i >= 9216 * 128) return;
    int row = i >> 7, gi = i & 127;
    int seg = gi >> 3, g = gi & 7;
    const float* src = (row < 8192) ? enc + ((size_t)row << 10)
                                    : Ua + ((size_t)(row - 8192) << 10);
    const float* p = src + (seg << 6) + ((g ^ (row & 7)) << 3);
    float4 v0 = *(const float4*)p;
    float4 v1 = *(const float4*)(p + 4);
    *(short8*)&dst[(size_t)i << 3] = cvt8(v0, v1);
}

// ---------------------------------------------------------------------------
// Attention-score GEMM, 256x128 tile, BK=64, global_load_lds staging,
// 512 threads = 8 waves (4M x 2N), wave tile 64x64. Fused tanh/Va epilogue.
__global__ __launch_bounds__(512) void k_attn2(
    const short* __restrict__ Abf, const short* __restrict__ Bbf,
    const float* __restrict__ Uab, const float* __restrict__ Wab,
    const float* __restrict__ qp, const float* __restrict__ Va,
    float* __restrict__ scores) {
    __shared__ short As[256 * 64];
    __shared__ short Bs[128 * 64];
    const int t = threadIdx.x;
    const int l = t & 63, w = t >> 6;
    const int wm = w >> 1, wn = w & 1;   // 4M x 2N
    const int lr = l & 15, lg = l >> 4;
    const int n0 = blockIdx.x * 128;
    const int r0 = blockIdx.y * 256;

    f32x4 acc[4][4];
#pragma unroll
    for (int i = 0; i < 4; ++i)
#pragma unroll
        for (int j = 0; j < 4; ++j) { f32x4 z = {0.f, 0.f, 0.f, 0.f}; acc[i][j] = z; }

    for (int seg = 0; seg < 16; ++seg) {
        // A: 2048 slots of 16B, 512 threads x 4; B: 1024 slots x 2
#pragma unroll
        for (int i = 0; i < 4; ++i) {
            int base = i * 512 + w * 64;      // wave-uniform slot base
            int s = base + l;
            gload16(Abf + (((size_t)r0 + (s >> 3)) << 10) + (seg << 6) + ((s & 7) << 3),
                    (void*)&As[base * 8]);
            if (i < 2)
                gload16(Bbf + (((size_t)8192 + n0 + (s >> 3)) << 10) + (seg << 6) + ((s & 7) << 3),
                        (void*)&Bs[base * 8]);
        }
        __syncthreads();
#pragma unroll
        for (int kh = 0; kh < 2; ++kh) {
            short8 a[4], b[4];
#pragma unroll
            for (int i = 0; i < 4; ++i) {
                int ra = wm * 64 + i * 16 + lr;
                a[i] = *(const short8*)&As[ra * 64 + (((kh * 4 + lg) ^ (ra & 7)) << 3)];
                int rb = wn * 64 + i * 16 + lr;
                b[i] = *(const short8*)&Bs[rb * 64 + (((kh * 4 + lg) ^ (rb & 7)) << 3)];
            }
#pragma unroll
            for (int i = 0; i < 4; ++i)
#pragma unroll
                for (int j = 0; j < 4; ++j)
                    acc[i][j] = __builtin_amdgcn_mfma_f32_16x16x32_bf16(a[i], b[j], acc[i][j], 0, 0, 0);
        }
        __syncthreads();
    }

    float va[4], ub[4];
#pragma unroll
    for (int j = 0; j < 4; ++j) {
        int h = n0 + wn * 64 + j * 16 + lr;
        va[j] = Va[h];
        ub[j] = Uab[h] + Wab[h];
    }
#pragma unroll
    for (int i = 0; i < 4; ++i)
#pragma unroll
        for (int r = 0; r < 4; ++r) {
            int row = r0 + wm * 64 + i * 16 + lg * 4 + r;
            const float* qpb = qp + (size_t)(row >> 7) * 1024;
            float s = 0.f;
#pragma unroll
            for (int j = 0; j < 4; ++j) {
                int h = n0 + wn * 64 + j * 16 + lr;
                s += va[j] * ftanh(acc[i][j][r] + qpb[h] + ub[j]);
            }
            s += __shfl_xor(s, 1);
            s += __shfl_xor(s, 2);
            s += __shfl_xor(s, 4);
            s += __shfl_xor(s, 8);
            if (lr == 0) atomicAdd(scores + row, s);
        }
}

// ---------------------------------------------------------------------------
// Skinny split-K GEMM (unchanged structure from R6).
__global__ __launch_bounds__(256) void k_sgemm(
    const float* __restrict__ A, int lda,
    const float* __restrict__ B0, int ldb0,
    const float* __restrict__ B1, int ldb1, int kyB1,
    float* __restrict__ C, int ldc, int Kblk) {
    __shared__ short As[64 * 64];
    __shared__ short Bs[64 * 64];
    const int t = threadIdx.x;
    const int l = t & 63, w = t >> 6;
    const int wm = w >> 1, wn = w & 1;
    const int lr = l & 15, lg = l >> 4;
    const int n0 = blockIdx.x * 64;
    const int ky = blockIdx.y;

    const float* Ab = A + (size_t)ky * Kblk;
    const float* Bb;
    int ldb;
    if (ky < kyB1) { Bb = B0 + (size_t)ky * Kblk; ldb = ldb0; }
    else           { Bb = B1 + (size_t)(ky - kyB1) * Kblk; ldb = ldb1; }

    f32x4 acc[2][2];
#pragma unroll
    for (int i = 0; i < 2; ++i)
#pragma unroll
        for (int j = 0; j < 2; ++j) { f32x4 z = {0.f, 0.f, 0.f, 0.f}; acc[i][j] = z; }

    for (int kt = 0; kt < Kblk; kt += 64) {
#pragma unroll
        for (int i = 0; i < 2; ++i) {
            int s = t + 256 * i, row = s >> 3, ch = s & 7;
            const float* p = Ab + (size_t)row * lda + kt + ch * 8;
            *(short8*)&As[row * 64 + ((ch ^ (row & 7)) << 3)] =
                cvt8(*(const float4*)p, *(const float4*)(p + 4));
            const float* q = Bb + (size_t)(n0 + row) * ldb + kt + ch * 8;
            *(short8*)&Bs[row * 64 + ((ch ^ (row & 7)) << 3)] =
                cvt8(*(const float4*)q, *(const float4*)(q + 4));
        }
        __syncthreads();
#pragma unroll
        for (int kh = 0; kh < 2; ++kh) {
            short8 a[2], b[2];
#pragma unroll
            for (int i = 0; i < 2; ++i) {
                int ra = wm * 32 + i * 16 + lr;
                a[i] = *(const short8*)&As[ra * 64 + (((kh * 4 + lg) ^ (ra & 7)) << 3)];
                int rb = wn * 32 + i * 16 + lr;
                b[i] = *(const short8*)&Bs[rb * 64 + (((kh * 4 + lg) ^ (rb & 7)) << 3)];
            }
#pragma unroll
            for (int i = 0; i < 2; ++i)
#pragma unroll
                for (int j = 0; j < 2; ++j)
                    acc[i][j] = __builtin_amdgcn_mfma_f32_16x16x32_bf16(a[i], b[j], acc[i][j], 0, 0, 0);
        }
        __syncthreads();
    }

#pragma unroll
    for (int i = 0; i < 2; ++i)
#pragma unroll
        for (int j = 0; j < 2; ++j)
#pragma unroll
            for (int r = 0; r < 4; ++r) {
                int R = wm * 32 + i * 16 + lg * 4 + r;
                int c = n0 + wn * 32 + j * 16 + lr;
                atomicAdd(&C[(size_t)R * ldc + c], acc[i][j][r]);
            }
}

// ---------------------------------------------------------------------------
// Fused softmax + context: one block per batch. scores row -> weights (out)
// and context -> xcat[:,1024:2048].
__global__ __launch_bounds__(256) void k_smctx(
    const float* __restrict__ scores, const float* __restrict__ enc,
    float* __restrict__ wout, float* __restrict__ xcat) {
    int b = blockIdx.x;
    int t = threadIdx.x;  // 256
    __shared__ float buf[128];
    __shared__ float wsb[128];
    if (t < 128) buf[t] = scores[b * 128 + t];
    __syncthreads();
    if (t < 64) buf[t] = fmaxf(buf[t], buf[t + 64]);
    __syncthreads();
    if (t < 32) buf[t] = fmaxf(buf[t], buf[t + 32]);
    __syncthreads();
    float m;
    {
        float v = buf[t & 31];
        for (int off = 16; off > 0; off >>= 1)
            v = fmaxf(v, __shfl_xor(v, off, 32));
        m = v;
    }
    __syncthreads();
    if (t < 128) wsb[t] = __expf(scores[b * 128 + t] - m);
    __syncthreads();
    if (t < 64) buf[t] = wsb[t] + wsb[t + 64];
    __syncthreads();
    if (t < 32) buf[t] += buf[t + 32];
    __syncthreads();
    float sum;
    {
        float v = buf[t & 31];
        for (int off = 16; off > 0; off >>= 1)
            v += __shfl_xor(v, off, 32);
        sum = v;
    }
    float inv = 1.f / sum;
    __syncthreads();
    if (t < 128) {
        wsb[t] *= inv;
        wout[b * 128 + t] = wsb[t];
    }
    __syncthreads();
    float acc[4] = {0.f, 0.f, 0.f, 0.f};
    for (int s = 0; s < 128; ++s) {
        float wv = wsb[s];
        const float* row = enc + ((size_t)b * 128 + s) * 1024;
#pragma unroll
        for (int j = 0; j < 4; ++j) acc[j] += wv * row[t + 256 * j];
    }
#pragma unroll
    for (int j = 0; j < 4; ++j) xcat[(size_t)b * 3072 + 1024 + t + 256 * j] = acc[j];
}

__global__ void k_lstm(const float* __restrict__ gates, const float* __restrict__ c0,
                       const float* __restrict__ b_ih, const float* __restrict__ b_hh,
                       float* __restrict__ h1, float* __restrict__ c1) {
    int idx = blockIdx.x * blockDim.x + threadIdx.x;  // 65536
    int b = idx >> 10, h = idx & 1023;
    const float* g = gates + (size_t)b * 4096;
    float iv = g[h] + b_ih[h] + b_hh[h];
    float fv = g[1024 + h] + b_ih[1024 + h] + b_hh[1024 + h];
    float gv = g[2048 + h] + b_ih[2048 + h] + b_hh[2048 + h];
    float ov = g[3072 + h] + b_ih[3072 + h] + b_hh[3072 + h];
    float si = 1.f / (1.f + expf(-iv));
    float sf = 1.f / (1.f + expf(-fv));
    float so = 1.f / (1.f + expf(-ov));
    float tg = tanhf(gv);
    float cc = sf * c0[idx] + si * tg;
    float hh = so * tanhf(cc);
    c1[idx] = cc;
    h1[idx] = hh;
}

// ---------------------------------------------------------------------------
extern "C" void kernel_launch(void* const* d_in, const int* in_sizes, int n_in,
                              void* d_out, int out_size, void* d_ws, size_t ws_size,
                              hipStream_t stream) {
    const int* idx = (const int*)d_in[0];
    const float* hidden = (const float*)d_in[1];
    const float* cell = (const float*)d_in[2];
    const float* enc = (const float*)d_in[3];
    const float* emb = (const float*)d_in[4];
    const float* Wa_w = (const float*)d_in[5];
    const float* Wa_b = (const float*)d_in[6];
    const float* Ua_w = (const float*)d_in[7];
    const float* Ua_b = (const float*)d_in[8];
    const float* Va_w = (const float*)d_in[9];
    // d_in[10] Va_b unused: softmax shift-invariant
    const float* W_ih = (const float*)d_in[11];
    const float* W_hh = (const float*)d_in[12];
    const float* b_ih = (const float*)d_in[13];
    const float* b_hh = (const float*)d_in[14];
    const float* out_w = (const float*)d_in[15];
    const float* out_b = (const float*)d_in[16];

    float* out = (float*)d_out;
    float* logits = out;                             // 64*32000
    float* h1 = out + 2048000;                       // 64*1024
    float* c1 = out + 2048000 + 65536;               // 64*1024
    float* wts = out + 2048000 + 65536 + 65536;      // 64*128

    // ws layout: [qp | scores | gates] (zeroed), xcat, then bf16 enc+Ua
    float* ws = (float*)d_ws;
    float* qp = ws;                      // 65536
    float* scores = ws + 65536;          // 8192
    float* gates = ws + 73728;           // 262144
    float* xcat = ws + 335872;           // 196608  (f32 scratch = 532480)
    short* encua_bf = (short*)(ws + 532480);  // 9216*1024 bf16 (enc rows then Ua)

    // 1. fused init (zero + logits bias + xcat gather)
    k_init<<<2520, 256, 0, stream>>>(out_b, logits, idx, emb, hidden, xcat,
                                     (float4*)ws);
    // 2. convert enc+Ua to swizzled bf16
    k_cvt_swz<<<4608, 256, 0, stream>>>(enc, Ua_w, encua_bf);
    // 3. qp = h0 @ Wa^T (Wa_b folded into attn epilogue), split-K x8
    k_sgemm<<<dim3(16, 8), 256, 0, stream>>>(hidden, 1024, Wa_w, 1024,
                                             nullptr, 0, 99, qp, 1024, 128);
    // 4. attention scores (256x128 tiles)
    k_attn2<<<dim3(8, 32), 512, 0, stream>>>(encua_bf, encua_bf, Ua_b, Wa_b,
                                             qp, Va_w, scores);
    // 5. softmax + context fused
    k_smctx<<<64, 256, 0, stream>>>(scores, enc, wts, xcat);
    // 6. gates = xcat @ [W_ih | W_hh]^T, split-K x12
    k_sgemm<<<dim3(64, 12), 256, 0, stream>>>(xcat, 3072, W_ih, 2048,
                                              W_hh, 1024, 8, gates, 4096, 256);
    // 7. LSTM pointwise
    k_lstm<<<256, 256, 0, stream>>>(gates, cell, b_ih, b_hh, h1, c1);
    // 8. logits += h1 @ out_w^T (bias pre-initialized), split-K x4
    k_sgemm<<<dim3(500, 4), 256, 0, stream>>>(h1, 1024, out_w, 1024,
                                              nullptr, 0, 99, logits, 32000, 256);
}